// Round 12
// baseline (750.662 us; speedup 1.0000x reference)
//
#include <hip/hip_runtime.h>

typedef unsigned short u16;
typedef unsigned int u32;
typedef __attribute__((ext_vector_type(8))) short bf16x8;
typedef __attribute__((ext_vector_type(4))) float f32x4;
typedef __attribute__((ext_vector_type(4))) u32 u32x4;

#define N_NODES 50000
#define N_EDGES 800000
#define NG_MAX ((N_EDGES + 15 * N_NODES) / 16)   // 96875 group upper bound

__device__ __forceinline__ float bf2f(u16 u) {
    union { u32 i; float f; } v; v.i = ((u32)u) << 16; return v.f;
}
__device__ __forceinline__ u16 f2bf(float f) {
    union { u32 i; float f; } v; v.f = f;
    u32 i = v.i;
    return (u16)((i + 0x7FFFu + ((i >> 16) & 1u)) >> 16);
}
// dtype-agnostic load: fl!=0 -> float32 buffer, else bf16 (u16) buffer
__device__ __forceinline__ float ldf(const void* p, int i, int fl) {
    return fl ? ((const float*)p)[i] : bf2f(((const u16*)p)[i]);
}
__device__ __forceinline__ int getflag(const int* flag) {
    return __builtin_amdgcn_readfirstlane(*flag);
}

struct P8 { const void* s[8]; };

// ---------------- fused: edge-degree histogram + dtype detection ----------------
__global__ __launch_bounds__(256) void k_deg_detect(
    const int* __restrict__ dst, int* __restrict__ cnt,
    const u16* __restrict__ xr, int* __restrict__ flag)
{
    int t = threadIdx.x;
    if (blockIdx.x < 3125) {
        int e = blockIdx.x * 256 + t;
        atomicAdd(&cnt[dst[e]], 1);   // 3125*256 == N_EDGES exactly
        return;
    }
    // block 3125: dtype detect on x[0..4095]
    __shared__ int sc[256];
    int c = 0;
    for (int i = t; i < 4096; i += 256) {
        u32 e = (xr[i] >> 7) & 0xFF;
        if (e >= 143) c++;
    }
    sc[t] = c;
    __syncthreads();
    for (int s = 128; s > 0; s >>= 1) {
        if (t < s) sc[t] += sc[t + s];
        __syncthreads();
    }
    if (t == 0) *flag = (sc[0] > 64) ? 1 : 0;   // 1 = float32, 0 = bf16
}

// ---------------- fused weight prep: transposes + bias concat + W2 folding ----------------
__global__ __launch_bounds__(256) void k_prep_all(
    P8 pw, P8 pb, u16* __restrict__ wcat1, u16* __restrict__ wcat2,
    float* __restrict__ bcat1, float* __restrict__ bcat2,
    const void* __restrict__ w2, const void* __restrict__ lng_,
    const void* __restrict__ lnb_, const void* __restrict__ b2_,
    const void* __restrict__ w1, u16* __restrict__ gt,
    float* __restrict__ csum, float* __restrict__ bwp,
    u32* __restrict__ w1pk, const int* __restrict__ flag)
{
    int fl = getflag(flag);
    int b = blockIdx.x, t = threadIdx.x;
    if (b < 512) {          // 8 x 128x128 weight transposes
        int gid = b * 256 + t;
        int wi = gid >> 14;
        int id = gid & 16383;
        int k = id >> 7, n = id & 127;
        u16* d = (wi < 4) ? (wcat1 + wi * 16384) : (wcat2 + (wi - 4) * 16384);
        d[n * 128 + k] = f2bf(ldf(pw.s[wi], id, fl));
    } else if (b < 516) {   // bias concat
        int tt = (b - 512) * 256 + t;
        float v = ldf(pb.s[tt >> 7], tt & 127, fl);
        if (tt < 512) bcat1[tt] = v; else bcat2[tt - 512] = v;
    } else {                // W2 folding (t = output column)
        if (t < 128) {
            float cs = 0.f, bw = 0.f;
            for (int f = 0; f < 128; f++) {
                float wv = ldf(w2, f * 128 + t, fl);
                float g = ldf(lng_, f, fl);
                float bb = ldf(lnb_, f, fl);
                u16 gwq = f2bf(g * wv);
                gt[t * 128 + f] = gwq;
                cs += bf2f(gwq);
                bw = fmaf(bb, wv, bw);
            }
            csum[t] = cs;
            bwp[t] = bw + ldf(b2_, t, fl);
            if (t < 64)
                w1pk[t] = (u32)f2bf(ldf(w1, 64 * 128 + t * 2, fl)) |
                          ((u32)f2bf(ldf(w1, 64 * 128 + t * 2 + 1, fl)) << 16);
        }
    }
}

// ---------------- CSR scan + group scan (single block, 1024 threads) ----------------
__global__ __launch_bounds__(1024) void k_scan(const int* __restrict__ cnt,
                                               int* __restrict__ row_start,
                                               int* __restrict__ nxt,
                                               int* __restrict__ gstart)
{
    __shared__ int wsum[16];
    __shared__ int wsum2[16];
    __shared__ int s_tot, s_tot2;
    int t = threadIdx.x, lane = t & 63, wid = t >> 6;
    int run = 0, run2 = 0;
    for (int base = 0; base < N_NODES; base += 8192) {
        int i0 = base + t * 8;
        int v[8], pre[8], gpre[8];
        int s = 0, gs = 0;
        #pragma unroll
        for (int j = 0; j < 8; j++) {
            int i = i0 + j;
            v[j] = (i < N_NODES) ? cnt[i] : 0;
            pre[j] = s;  s += v[j];
            gpre[j] = gs; gs += (v[j] + 15) >> 4;
        }
        int tsum = s, gsum = gs;
        int sc = tsum, sc2 = gsum;
        #pragma unroll
        for (int off = 1; off < 64; off <<= 1) {
            int o = __shfl_up(sc, off);
            int o2 = __shfl_up(sc2, off);
            if (lane >= off) { sc += o; sc2 += o2; }
        }
        if (lane == 63) { wsum[wid] = sc; wsum2[wid] = sc2; }
        __syncthreads();
        if (t == 0) {
            int acc2 = 0, acc3 = 0;
            #pragma unroll
            for (int k2 = 0; k2 < 16; k2++) {
                int vv = wsum[k2]; wsum[k2] = acc2; acc2 += vv;
                int v2 = wsum2[k2]; wsum2[k2] = acc3; acc3 += v2;
            }
            s_tot = acc2; s_tot2 = acc3;
        }
        __syncthreads();
        int texcl = run + wsum[wid] + (sc - tsum);
        int gexcl = run2 + wsum2[wid] + (sc2 - gsum);
        #pragma unroll
        for (int j = 0; j < 8; j++) {
            int i = i0 + j;
            if (i < N_NODES) {
                int ex = texcl + pre[j];
                row_start[i] = ex; nxt[i] = ex;
                gstart[i] = gexcl + gpre[j];
            }
        }
        run += s_tot; run2 += s_tot2;
        __syncthreads();
    }
    if (t == 0) { row_start[N_NODES] = run; gstart[N_NODES] = run2; }
}

// ---------------- group list fill: glist[g] = (node, absolute edge base) ------
__global__ __launch_bounds__(256) void k_glist(
    const int* __restrict__ rowst, const int* __restrict__ gstart,
    int2* __restrict__ glist)
{
    int n = blockIdx.x * 256 + threadIdx.x;
    if (n >= N_NODES) return;
    int rs = rowst[n], re = rowst[n + 1];
    int gs = gstart[n];
    int cnt = (re - rs + 15) >> 4;
    for (int k = 0; k < cnt; k++)
        glist[gs + k] = make_int2(n, rs + k * 16);
}

// ---------------- fused: node lin1 (bf16 y) + CSR scatter w/ payload ----------------
__global__ __launch_bounds__(256) void k_lin1_scatter(
    const void* __restrict__ x, const void* __restrict__ w1,
    const void* __restrict__ b1, u16* __restrict__ y,
    const int* __restrict__ dst, const int* __restrict__ srcp,
    const void* __restrict__ ea, int* __restrict__ nxt,
    int2* __restrict__ csr, const int* __restrict__ flag)
{
    __shared__ float sx[2][64];
    int fl = getflag(flag);
    int t = threadIdx.x;
    if (blockIdx.x >= 782) {   // scatter
        int e = (blockIdx.x - 782) * 256 + t;
        if (e < N_EDGES) {
            int p = atomicAdd(&nxt[dst[e]], 1);
            int2 v;
            v.x = srcp[e];
            v.y = __float_as_int(ldf(ea, e, fl));
            csr[p] = v;
        }
        return;
    }
    // lin1
    int col = t & 127, half = t >> 7;
    float wreg[64];
    #pragma unroll
    for (int k = 0; k < 64; k++) wreg[k] = ldf(w1, k * 128 + col, fl);
    float bias = ldf(b1, col, fl);
    int base = blockIdx.x * 64;
    for (int it = 0; it < 32; ++it) {
        __syncthreads();
        if (t < 128) {
            int nh = base + it * 2 + (t >> 6);
            sx[t >> 6][t & 63] = (nh < N_NODES) ? ldf(x, nh * 64 + (t & 63), fl) : 0.f;
        }
        __syncthreads();
        float acc = bias;
        #pragma unroll
        for (int k = 0; k < 64; k++) acc = fmaf(sx[half][k], wreg[k], acc);
        int n = base + it * 2 + half;
        if (n < N_NODES) y[(size_t)n * 128 + col] = f2bf(acc);
    }
}

// ---------------- R12 embed: wave per group, 1024-thread blocks + idle skip ----
// R11 (512-thread) win came from preamble amortization (186->141us), not the
// occupancy cap. Same mechanism, doubled again: 16 waves share one 34.8KB sB
// staging (6055 blocks, 2 blocks/CU x 16 waves = 32/CU = 100% cap). Plus:
// blocks entirely past ng (~28% -- NG_MAX 96875 vs actual ng ~69k) skip the
// staging entirely (wave-uniform blockIdx test BEFORE any barrier).
// Body byte-identical single-shot (R5/R10 rule: no loop-carried state).
__global__ __launch_bounds__(1024) void k_embed_grp(
    const u16* __restrict__ y, const int2* __restrict__ csr,
    const int* __restrict__ rowst, const int* __restrict__ gstart,
    const int2* __restrict__ glist,
    const u16* __restrict__ gt, const u32* __restrict__ w1pk,
    const float* __restrict__ csum, const float* __restrict__ bwp,
    float* __restrict__ h1stage, float* __restrict__ vacc)
{
    __shared__ u16 sB[128 * 136];
    __shared__ u32 sW1[64];
    __shared__ float sCSf[128];
    __shared__ float sBWf[128];
    int ng = gstart[N_NODES];
    if (blockIdx.x * 16 >= ng) return;     // fully idle block: skip staging (uniform)
    int t = threadIdx.x;
    for (int c = t; c < 128 * 32; c += 1024) {
        int row = c >> 5, ch = c & 31;
        *(ushort4*)&sB[row * 136 + ch * 4] = *(const ushort4*)&gt[row * 128 + ch * 4];
    }
    if (t < 64) sW1[t] = w1pk[t];
    if (t < 128) sCSf[t] = csum[t];
    else if (t < 256) sBWf[t - 128] = bwp[t - 128];
    int l = t & 63, w = t >> 6;            // w in [0,16)
    int m = l & 15, q = l >> 4;
    __syncthreads();                       // all threads reach barrier first
    int gid = blockIdx.x * 16 + w;
    if (gid >= ng) return;                 // overlaunched waves exit after barrier
    int2 ge = glist[gid];
    int node = ge.x, base = ge.y;
    int re = rowst[node + 1];
    int row = base + m;
    if (row >= re) row = re - 1;           // pad lanes masked via rs2=0 below
    int2 sa = csr[row];
    float av = __int_as_float(sa.y);
    const u16* yr = y + (size_t)sa.x * 128 + q * 8;

    // unpack + relu + LN1 stats
    bf16x8 efrag[4];
    float s1 = 0.f, s2 = 0.f;
    #pragma unroll
    for (int kb = 0; kb < 4; kb++) {
        u32x4 yu = __builtin_bit_cast(u32x4, *(const bf16x8*)(yr + kb * 32));
        u32x4 wv4 = *(const u32x4*)&sW1[kb * 16 + q * 4];
        u32x4 ep;
        #pragma unroll
        for (int j2 = 0; j2 < 4; j2++) {
            u32 yw = yu[j2];
            u32 ww = wv4[j2];
            float y0 = __uint_as_float(yw << 16);
            float y1 = __uint_as_float(yw & 0xffff0000u);
            float w0 = __uint_as_float(ww << 16);
            float w1v = __uint_as_float(ww & 0xffff0000u);
            float u0 = fmaxf(fmaf(av, w0, y0), 0.f);
            float u1 = fmaxf(fmaf(av, w1v, y1), 0.f);
            s1 += u0; s2 = fmaf(u0, u0, s2);
            s1 += u1; s2 = fmaf(u1, u1, s2);
            ep[j2] = __builtin_amdgcn_perm(__float_as_uint(u1),
                                           __float_as_uint(u0), 0x07060302u);
        }
        efrag[kb] = __builtin_bit_cast(bf16x8, ep);
    }
    s1 += __shfl_xor(s1, 16); s2 += __shfl_xor(s2, 16);
    s1 += __shfl_xor(s1, 32); s2 += __shfl_xor(s2, 32);
    float mu = s1 * (1.f / 128.f);
    float alpha = rsqrtf(s2 * (1.f / 128.f) - mu * mu + 1e-5f);
    float beta = -mu * alpha;

    f32x4 zf = {0.f, 0.f, 0.f, 0.f};
    f32x4 acc[8];
    #pragma unroll
    for (int nb = 0; nb < 8; nb++) acc[nb] = zf;
    #pragma unroll
    for (int nb = 0; nb < 8; nb++) {
        const u16* grow = &sB[(nb * 16 + m) * 136 + q * 8];
        #pragma unroll
        for (int kb = 0; kb < 4; kb++) {
            bf16x8 gfrag = *(const bf16x8*)(grow + kb * 32);
            acc[nb] = __builtin_amdgcn_mfma_f32_16x16x32_bf16(gfrag, efrag[kb], acc[nb], 0, 0, 0);
        }
    }
    float t1 = 0.f, t2 = 0.f;
    #pragma unroll
    for (int nb = 0; nb < 8; nb++) {
        float4 cs4 = *(const float4*)&sCSf[nb * 16 + q * 4];
        float4 bw4 = *(const float4*)&sBWf[nb * 16 + q * 4];
        float csa[4] = {cs4.x, cs4.y, cs4.z, cs4.w};
        float bwa[4] = {bw4.x, bw4.y, bw4.z, bw4.w};
        #pragma unroll
        for (int r = 0; r < 4; r++) {
            float z = fmaxf(fmaf(alpha, acc[nb][r], fmaf(beta, csa[r], bwa[r])), 0.f);
            acc[nb][r] = z;
            t1 += z; t2 = fmaf(z, z, t2);
        }
    }
    t1 += __shfl_xor(t1, 16); t2 += __shfl_xor(t2, 16);
    t1 += __shfl_xor(t1, 32); t2 += __shfl_xor(t2, 32);
    float mu2 = t1 * (1.f / 128.f);
    float rs2 = rsqrtf(t2 * (1.f / 128.f) - mu2 * mu2 + 1e-5f);
    if (base + m >= re) rs2 = 0.f;         // mask pad edges (lane's edge = m)
    float Vc = rs2 * mu2;

    // tree-reduce acc*rs2 over the 16 edge columns
    bool sel0 = (m & 1), sel1 = (m & 2), sel2 = (m & 4), sel3 = (m & 8);
    float sacc0, sacc1;
    {
        float s16v[16];
        #pragma unroll
        for (int k = 0; k < 16; k++) {
            int nb = k >> 1, rh = (k & 1) << 1;
            float a = acc[nb][rh] * rs2, b = acc[nb][rh + 1] * rs2;
            float keep = sel0 ? b : a;
            float send = sel0 ? a : b;
            s16v[k] = keep + __shfl_xor(send, 1);
        }
        float s8v[8];
        #pragma unroll
        for (int nb = 0; nb < 8; nb++) {
            float a = s16v[nb * 2], b = s16v[nb * 2 + 1];
            float keep = sel1 ? b : a;
            float send = sel1 ? a : b;
            s8v[nb] = keep + __shfl_xor(send, 2);
        }
        float s4v[4];
        #pragma unroll
        for (int k = 0; k < 4; k++) {
            float a = s8v[k * 2], b = s8v[k * 2 + 1];
            float keep = sel2 ? b : a;
            float send = sel2 ? a : b;
            s4v[k] = keep + __shfl_xor(send, 4);
        }
        float a0 = s4v[0], b0 = s4v[1];
        float keep0 = sel3 ? b0 : a0, send0 = sel3 ? a0 : b0;
        sacc0 = keep0 + __shfl_xor(send0, 8);
        float a1 = s4v[2], b1 = s4v[3];
        float keep1 = sel3 ? b1 : a1, send1 = sel3 ? a1 : b1;
        sacc1 = keep1 + __shfl_xor(send1, 8);
    }
    // V reduce over the 16 edges (m dim)
    Vc += __shfl_xor(Vc, 1); Vc += __shfl_xor(Vc, 2);
    Vc += __shfl_xor(Vc, 4); Vc += __shfl_xor(Vc, 8);
    if (l == 0) unsafeAtomicAdd(&vacc[node], Vc);
    #pragma unroll
    for (int k = 0; k < 2; k++) {
        int nb = (k << 2) | (((m >> 3) & 1) << 1) | ((m >> 2) & 1);
        int f = nb * 16 + q * 4 + (m & 3);
        float sv = (k == 0) ? sacc0 : sacc1;
        unsafeAtomicAdd(&h1stage[(size_t)node * 128 + f], sv);
    }
}

// ---------------- embed finalize: h1 = bf16(g*(S - V) + d*b) ----------------
__global__ __launch_bounds__(256) void k_embed_fin(
    const float* __restrict__ h1stage, const float* __restrict__ vacc,
    const int* __restrict__ rowst,
    const void* __restrict__ lng, const void* __restrict__ lnb,
    u16* __restrict__ h1, const int* __restrict__ flag)
{
    int fl = getflag(flag);
    int idx = blockIdx.x * 256 + threadIdx.x;   // 6250 blocks * 256 = 50000*32
    int node = idx >> 5;
    int f4 = (idx & 31) * 4;
    float4 sv = *(const float4*)&h1stage[(size_t)node * 128 + f4];
    float V = vacc[node];
    float dg = (float)(rowst[node + 1] - rowst[node]);
    ushort4 o;
    o.x = f2bf(fmaf(ldf(lng, f4 + 0, fl), sv.x - V, dg * ldf(lnb, f4 + 0, fl)));
    o.y = f2bf(fmaf(ldf(lng, f4 + 1, fl), sv.y - V, dg * ldf(lnb, f4 + 1, fl)));
    o.z = f2bf(fmaf(ldf(lng, f4 + 2, fl), sv.z - V, dg * ldf(lnb, f4 + 2, fl)));
    o.w = f2bf(fmaf(ldf(lng, f4 + 3, fl), sv.w - V, dg * ldf(lnb, f4 + 3, fl)));
    *(ushort4*)&h1[(size_t)node * 128 + f4] = o;
}

// ---------------- fused q/k/v/skip projection GEMM (bf16 h input) ----------------
__global__ __launch_bounds__(256) void k_proj(
    const u16* __restrict__ hin, const u16* __restrict__ wt,
    const float* __restrict__ bcat, u16* __restrict__ outp)
{
    __shared__ u16 sA[64 * 136];
    __shared__ u16 sB[128 * 136];
    int t = threadIdx.x;
    int l = t & 63, w = t >> 6;
    int m = l & 15, q = l >> 4;
    int rowbase = blockIdx.x * 64;
    for (int c = t; c < 64 * 32; c += 256) {
        int row = c >> 5, ch = c & 31;
        int gr = rowbase + row;
        ushort4 pk = make_ushort4(0, 0, 0, 0);
        if (gr < N_NODES) pk = *(const ushort4*)&hin[(size_t)gr * 128 + ch * 4];
        *(ushort4*)&sA[row * 136 + ch * 4] = pk;
    }
    __syncthreads();
    bf16x8 afrag[4];
    #pragma unroll
    for (int kb = 0; kb < 4; kb++)
        afrag[kb] = *(const bf16x8*)&sA[(w * 16 + m) * 136 + kb * 32 + q * 8];

    f32x4 zf = {0.f, 0.f, 0.f, 0.f};
    for (int g = 0; g < 4; ++g) {
        __syncthreads();
        for (int c = t; c < 128 * 32; c += 256) {
            int row = c >> 5, ch = c & 31;
            *(ushort4*)&sB[row * 136 + ch * 4] = *(const ushort4*)&wt[(g * 128 + row) * 128 + ch * 4];
        }
        __syncthreads();
        f32x4 acc[8];
        #pragma unroll
        for (int nb = 0; nb < 8; nb++) acc[nb] = zf;
        #pragma unroll
        for (int nb = 0; nb < 8; nb++) {
            const u16* brow = &sB[(nb * 16 + m) * 136 + q * 8];
            #pragma unroll
            for (int kb = 0; kb < 4; kb++) {
                bf16x8 bfrag = *(const bf16x8*)(brow + kb * 32);
                acc[nb] = __builtin_amdgcn_mfma_f32_16x16x32_bf16(afrag[kb], bfrag, acc[nb], 0, 0, 0);
            }
        }
        #pragma unroll
        for (int nb = 0; nb < 8; nb++) {
            int col = g * 128 + nb * 16 + m;
            float bb = bcat[col];
            #pragma unroll
            for (int r = 0; r < 4; r++) {
                int row = rowbase + w * 16 + q * 4 + r;
                if (row < N_NODES) outp[(size_t)row * 512 + col] = f2bf(acc[nb][r] + bb);
            }
        }
    }
}

// ---------------- attention: wave per dst node, 4 subs x 16 lanes, no-max exp ----------------
__global__ __launch_bounds__(256) void k_attn(
    const u16* __restrict__ qkvs,
    const int* __restrict__ rowst, const int2* __restrict__ csr,
    const void* __restrict__ wep, u16* __restrict__ hout,
    const int* __restrict__ flag)
{
    int fl = getflag(flag);
    int t = threadIdx.x;
    int l = t & 63, w = t >> 6;
    int dstn = blockIdx.x * 4 + w;        // grid*4 == N exactly
    int lane16 = l & 15, sub = l >> 4;
    int f0 = lane16 * 8;                  // 8 features per lane
    const float scale = 0.17677669529663687f;  // 1/sqrt(32)

    bf16x8 q8 = *(const bf16x8*)&qkvs[(size_t)dstn * 512 + f0];
    float qf[8], wef[8];
    if (fl) {                              // vectorized wep load (wave-uniform branch)
        float4 w0 = *(const float4*)((const float*)wep + f0);
        float4 w1v = *(const float4*)((const float*)wep + f0 + 4);
        wef[0] = w0.x; wef[1] = w0.y; wef[2] = w0.z; wef[3] = w0.w;
        wef[4] = w1v.x; wef[5] = w1v.y; wef[6] = w1v.z; wef[7] = w1v.w;
    } else {
        bf16x8 w8 = *(const bf16x8*)((const u16*)wep + f0);
        #pragma unroll
        for (int j = 0; j < 8; j++) wef[j] = bf2f((u16)w8[j]);
    }
    #pragma unroll
    for (int j = 0; j < 8; j++) qf[j] = bf2f((u16)q8[j]) * scale;

    float si = 0.f;
    float a8[8];
    #pragma unroll
    for (int j = 0; j < 8; j++) a8[j] = 0.f;

    int rs = rowst[dstn], re = rowst[dstn + 1];
    int i = rs + sub;
    for (; i + 4 < re; i += 8) {
        int2 sa = csr[i];
        int2 sb = csr[i + 4];
        float ava = __int_as_float(sa.y);
        float avb = __int_as_float(sb.y);
        const u16* sra = &qkvs[(size_t)sa.x * 512 + f0];
        const u16* srb = &qkvs[(size_t)sb.x * 512 + f0];
        bf16x8 k8a = *(const bf16x8*)(sra + 128);
        bf16x8 v8a = *(const bf16x8*)(sra + 256);
        bf16x8 k8b = *(const bf16x8*)(srb + 128);
        bf16x8 v8b = *(const bf16x8*)(srb + 256);
        float pa = 0.f, pb = 0.f;
        float vea[8], veb[8];
        #pragma unroll
        for (int j = 0; j < 8; j++) {
            pa = fmaf(qf[j], fmaf(ava, wef[j], bf2f((u16)k8a[j])), pa);
            pb = fmaf(qf[j], fmaf(avb, wef[j], bf2f((u16)k8b[j])), pb);
            vea[j] = fmaf(ava, wef[j], bf2f((u16)v8a[j]));
            veb[j] = fmaf(avb, wef[j], bf2f((u16)v8b[j]));
        }
        pa += __shfl_xor(pa, 1); pb += __shfl_xor(pb, 1);
        pa += __shfl_xor(pa, 2); pb += __shfl_xor(pb, 2);
        float pea = __expf(pa);
        float peb = __expf(pb);
        si += pea + peb;
        #pragma unroll
        for (int j = 0; j < 8; j++)
            a8[j] = fmaf(pea, vea[j], fmaf(peb, veb[j], a8[j]));
    }
    if (i < re) {   // tail single edge
        int2 sa = csr[i];
        float av = __int_as_float(sa.y);
        const u16* sr = &qkvs[(size_t)sa.x * 512 + f0];
        bf16x8 k8 = *(const bf16x8*)(sr + 128);
        bf16x8 v8 = *(const bf16x8*)(sr + 256);
        float p = 0.f;
        float ve[8];
        #pragma unroll
        for (int j = 0; j < 8; j++) {
            p = fmaf(qf[j], fmaf(av, wef[j], bf2f((u16)k8[j])), p);
            ve[j] = fmaf(av, wef[j], bf2f((u16)v8[j]));
        }
        p += __shfl_xor(p, 1); p += __shfl_xor(p, 2);
        float pe = __expf(p);
        si += pe;
        #pragma unroll
        for (int j = 0; j < 8; j++) a8[j] = fmaf(pe, ve[j], a8[j]);
    }
    #pragma unroll
    for (int off = 16; off < 64; off <<= 1) {
        si += __shfl_xor(si, off);
        #pragma unroll
        for (int j = 0; j < 8; j++) a8[j] += __shfl_xor(a8[j], off);
    }
    if (sub == 0) {
        float inv = 1.f / (si + 1e-16f);
        bf16x8 s8 = *(const bf16x8*)&qkvs[(size_t)dstn * 512 + 384 + f0];
        ushort4 p0, p1;
        float o[8];
        #pragma unroll
        for (int j = 0; j < 8; j++)
            o[j] = fmaxf(fmaf(a8[j], inv, bf2f((u16)s8[j])), 0.f);
        p0.x = f2bf(o[0]); p0.y = f2bf(o[1]); p0.z = f2bf(o[2]); p0.w = f2bf(o[3]);
        p1.x = f2bf(o[4]); p1.y = f2bf(o[5]); p1.z = f2bf(o[6]); p1.w = f2bf(o[7]);
        u16* hr = hout + (size_t)dstn * 128 + f0;
        *(ushort4*)hr = p0;
        *(ushort4*)(hr + 4) = p1;
    }
}

// ---------------- global mean pool (bf16 h input, u32 feature pairs) ----------------
__global__ __launch_bounds__(256) void k_pool(
    const u16* __restrict__ h, const int* __restrict__ batch,
    float* __restrict__ gsum, float* __restrict__ gcnt)
{
    __shared__ float ssum[8 * 128];
    __shared__ float scnt[8];
    int t = threadIdx.x;
    for (int i = t; i < 8 * 128; i += 256) ssum[i] = 0.f;
    if (t < 8) scnt[t] = 0.f;
    __syncthreads();
    int f2 = (t & 63) * 2, quarter = t >> 6;
    int per = (N_NODES + gridDim.x - 1) / gridDim.x;
    int lo = blockIdx.x * per;
    int hi = lo + per; if (hi > N_NODES) hi = N_NODES;
    float r0 = 0.f, r1 = 0.f, rcnt = 0.f; int rg = -1;
    for (int n = lo + quarter; n < hi; n += 4) {
        int g = batch[n];
        if (g != rg) {
            if (rg >= 0) {
                atomicAdd(&ssum[rg * 128 + f2], r0);
                atomicAdd(&ssum[rg * 128 + f2 + 1], r1);
                if (f2 == 0) atomicAdd(&scnt[rg], rcnt);
            }
            rg = g; r0 = 0.f; r1 = 0.f; rcnt = 0.f;
        }
        u32 hv = *(const u32*)&h[(size_t)n * 128 + f2];
        r0 += bf2f((u16)(hv & 0xffff));
        r1 += bf2f((u16)(hv >> 16));
        rcnt += 1.f;
    }
    if (rg >= 0) {
        atomicAdd(&ssum[rg * 128 + f2], r0);
        atomicAdd(&ssum[rg * 128 + f2 + 1], r1);
        if (f2 == 0) atomicAdd(&scnt[rg], rcnt);
    }
    __syncthreads();
    for (int i = t; i < 8 * 128; i += 256) unsafeAtomicAdd(&gsum[i], ssum[i]);
    if (t < 8) unsafeAtomicAdd(&gcnt[t], scnt[t]);
}

__global__ void k_out(const float* __restrict__ gsum, const float* __restrict__ gcnt,
                      void* __restrict__ outp, const int* __restrict__ flag) {
    int fl = getflag(flag);
    int t = threadIdx.x;  // 1024
    float c = fmaxf(gcnt[t >> 7], 1.f);
    float v = gsum[t] / c;
    if (fl) ((float*)outp)[t] = v;
    else ((u16*)outp)[t] = f2bf(v);
}

extern "C" void kernel_launch(void* const* d_in, const int* in_sizes, int n_in,
                              void* d_out, int out_size, void* d_ws, size_t ws_size,
                              hipStream_t stream)
{
    (void)in_sizes; (void)n_in; (void)out_size; (void)ws_size;
    const void* x    = d_in[0];
    const int* ei    = (const int*)d_in[1];
    const void* ea   = d_in[2];
    const int* batch = (const int*)d_in[3];
    const void* w1   = d_in[4];
    const void* b1   = d_in[5];
    const void* lng  = d_in[6];
    const void* lnb  = d_in[7];
    const void* w2   = d_in[8];
    const void* b2   = d_in[9];
    const int* srcp = ei;
    const int* dstp = ei + N_EDGES;

    char* wsb = (char*)d_ws;
    size_t cur = 0;
    auto alloc = [&](size_t sz) -> void* {
        void* p = wsb + cur;
        cur += (sz + 255) & ~(size_t)255;
        return p;
    };
    u16*   y      = (u16*)  alloc((size_t)N_NODES * 128 * 2);
    u16*   h1     = (u16*)  alloc((size_t)N_NODES * 128 * 2);   // reused as h3
    u16*   h2     = (u16*)  alloc((size_t)N_NODES * 128 * 2);
    u16*   qkvs   = (u16*)  alloc((size_t)N_NODES * 512 * 2);
    int2*  csr    = (int2*) alloc((size_t)N_EDGES * 8);
    u16*   gt     = (u16*)  alloc(128 * 128 * 2);
    u16*   wcat1  = (u16*)  alloc(512 * 128 * 2);
    u16*   wcat2  = (u16*)  alloc(512 * 128 * 2);
    float* csum   = (float*)alloc(128 * 4);
    float* bwp    = (float*)alloc(128 * 4);
    u32*   w1pk   = (u32*)  alloc(64 * 4);
    float* bcat1  = (float*)alloc(512 * 4);
    float* bcat2  = (float*)alloc(512 * 4);
    int*   cntdeg = (int*)  alloc((size_t)N_NODES * 4);
    int*   rowst  = (int*)  alloc((size_t)(N_NODES + 1) * 4);
    int*   nxt    = (int*)  alloc((size_t)N_NODES * 4);
    float* gsum   = (float*)alloc((8 * 128 + 8) * 4);
    int*   dtflag = (int*)  alloc(256);
    // group-embed buffers (~26.8 MB total)
    float* h1stage = (float*)alloc((size_t)N_NODES * 128 * 4);
    float* vacc    = (float*)alloc((size_t)N_NODES * 4);
    int*   gstart  = (int*)  alloc((size_t)(N_NODES + 1) * 4);
    int2*  glist   = (int2*) alloc((size_t)NG_MAX * 8);
    u16*   h3 = h1;   // h1 is dead after first k_proj

    hipMemsetAsync(cntdeg, 0, (size_t)N_NODES * 4, stream);
    hipMemsetAsync(gsum, 0, (8 * 128 + 8) * 4, stream);
    hipMemsetAsync(h1stage, 0, (size_t)N_NODES * 128 * 4 + 256 + (size_t)N_NODES * 4, stream);

    P8 pw; P8 pb;
    pw.s[0] = d_in[10]; pw.s[1] = d_in[12]; pw.s[2] = d_in[14]; pw.s[3] = d_in[17];
    pw.s[4] = d_in[19]; pw.s[5] = d_in[21]; pw.s[6] = d_in[23]; pw.s[7] = d_in[26];
    pb.s[0] = d_in[11]; pb.s[1] = d_in[13]; pb.s[2] = d_in[15]; pb.s[3] = d_in[18];
    pb.s[4] = d_in[20]; pb.s[5] = d_in[22]; pb.s[6] = d_in[24]; pb.s[7] = d_in[27];

    k_deg_detect<<<3126, 256, 0, stream>>>(dstp, cntdeg, (const u16*)x, dtflag);
    k_prep_all<<<517, 256, 0, stream>>>(pw, pb, wcat1, wcat2, bcat1, bcat2,
                                        w2, lng, lnb, b2, w1, gt, csum, bwp, w1pk, dtflag);
    k_scan<<<1, 1024, 0, stream>>>(cntdeg, rowst, nxt, gstart);
    k_glist<<<196, 256, 0, stream>>>(rowst, gstart, glist);
    k_lin1_scatter<<<3907, 256, 0, stream>>>(x, w1, b1, y, dstp, srcp, ea, nxt, csr, dtflag);
    k_embed_grp<<<(NG_MAX + 15) / 16, 1024, 0, stream>>>(y, csr, rowst, gstart, glist,
                                                         gt, w1pk, csum, bwp, h1stage, vacc);
    k_embed_fin<<<6250, 256, 0, stream>>>(h1stage, vacc, rowst, lng, lnb, h1, dtflag);
    k_proj<<<782, 256, 0, stream>>>(h1, wcat1, bcat1, qkvs);
    k_attn<<<12500, 256, 0, stream>>>(qkvs, rowst, csr, d_in[16], h2, dtflag);
    k_proj<<<782, 256, 0, stream>>>(h2, wcat2, bcat2, qkvs);
    k_attn<<<12500, 256, 0, stream>>>(qkvs, rowst, csr, d_in[25], h3, dtflag);
    k_pool<<<128, 256, 0, stream>>>(h3, batch, gsum, gsum + 8 * 128);
    k_out<<<1, 1024, 0, stream>>>(gsum, gsum + 8 * 128, d_out, dtflag);
}

// Round 14
// 728.140 us; speedup vs baseline: 1.0309x; 1.0309x over previous
//
#include <hip/hip_runtime.h>

typedef unsigned short u16;
typedef unsigned int u32;
typedef __attribute__((ext_vector_type(8))) short bf16x8;
typedef __attribute__((ext_vector_type(4))) float f32x4;
typedef __attribute__((ext_vector_type(4))) u32 u32x4;

#define N_NODES 50000
#define N_EDGES 800000
#define NG_MAX ((N_EDGES + 15 * N_NODES) / 16)   // 96875 group upper bound

__device__ __forceinline__ float bf2f(u16 u) {
    union { u32 i; float f; } v; v.i = ((u32)u) << 16; return v.f;
}
__device__ __forceinline__ u16 f2bf(float f) {
    union { u32 i; float f; } v; v.f = f;
    u32 i = v.i;
    return (u16)((i + 0x7FFFu + ((i >> 16) & 1u)) >> 16);
}
// dtype-agnostic load: fl!=0 -> float32 buffer, else bf16 (u16) buffer
__device__ __forceinline__ float ldf(const void* p, int i, int fl) {
    return fl ? ((const float*)p)[i] : bf2f(((const u16*)p)[i]);
}
__device__ __forceinline__ int getflag(const int* flag) {
    return __builtin_amdgcn_readfirstlane(*flag);
}

struct P8 { const void* s[8]; };

// ---------------- fused: edge-degree histogram + dtype detection ----------------
__global__ __launch_bounds__(256) void k_deg_detect(
    const int* __restrict__ dst, int* __restrict__ cnt,
    const u16* __restrict__ xr, int* __restrict__ flag)
{
    int t = threadIdx.x;
    if (blockIdx.x < 3125) {
        int e = blockIdx.x * 256 + t;
        atomicAdd(&cnt[dst[e]], 1);   // 3125*256 == N_EDGES exactly
        return;
    }
    // block 3125: dtype detect on x[0..4095]
    __shared__ int sc[256];
    int c = 0;
    for (int i = t; i < 4096; i += 256) {
        u32 e = (xr[i] >> 7) & 0xFF;
        if (e >= 143) c++;
    }
    sc[t] = c;
    __syncthreads();
    for (int s = 128; s > 0; s >>= 1) {
        if (t < s) sc[t] += sc[t + s];
        __syncthreads();
    }
    if (t == 0) *flag = (sc[0] > 64) ? 1 : 0;   // 1 = float32, 0 = bf16
}

// ---------------- fused weight prep: transposes + bias concat + W2 folding ----------------
__global__ __launch_bounds__(256) void k_prep_all(
    P8 pw, P8 pb, u16* __restrict__ wcat1, u16* __restrict__ wcat2,
    float* __restrict__ bcat1, float* __restrict__ bcat2,
    const void* __restrict__ w2, const void* __restrict__ lng_,
    const void* __restrict__ lnb_, const void* __restrict__ b2_,
    const void* __restrict__ w1, u16* __restrict__ gt,
    float* __restrict__ csum, float* __restrict__ bwp,
    u32* __restrict__ w1pk, const int* __restrict__ flag)
{
    int fl = getflag(flag);
    int b = blockIdx.x, t = threadIdx.x;
    if (b < 512) {          // 8 x 128x128 weight transposes
        int gid = b * 256 + t;
        int wi = gid >> 14;
        int id = gid & 16383;
        int k = id >> 7, n = id & 127;
        u16* d = (wi < 4) ? (wcat1 + wi * 16384) : (wcat2 + (wi - 4) * 16384);
        d[n * 128 + k] = f2bf(ldf(pw.s[wi], id, fl));
    } else if (b < 516) {   // bias concat
        int tt = (b - 512) * 256 + t;
        float v = ldf(pb.s[tt >> 7], tt & 127, fl);
        if (tt < 512) bcat1[tt] = v; else bcat2[tt - 512] = v;
    } else {                // W2 folding (t = output column)
        if (t < 128) {
            float cs = 0.f, bw = 0.f;
            for (int f = 0; f < 128; f++) {
                float wv = ldf(w2, f * 128 + t, fl);
                float g = ldf(lng_, f, fl);
                float bb = ldf(lnb_, f, fl);
                u16 gwq = f2bf(g * wv);
                gt[t * 128 + f] = gwq;
                cs += bf2f(gwq);
                bw = fmaf(bb, wv, bw);
            }
            csum[t] = cs;
            bwp[t] = bw + ldf(b2_, t, fl);
            if (t < 64)
                w1pk[t] = (u32)f2bf(ldf(w1, 64 * 128 + t * 2, fl)) |
                          ((u32)f2bf(ldf(w1, 64 * 128 + t * 2 + 1, fl)) << 16);
        }
    }
}

// ---------------- CSR scan + group scan (single block, 1024 threads) ----------------
__global__ __launch_bounds__(1024) void k_scan(const int* __restrict__ cnt,
                                               int* __restrict__ row_start,
                                               int* __restrict__ nxt,
                                               int* __restrict__ gstart)
{
    __shared__ int wsum[16];
    __shared__ int wsum2[16];
    __shared__ int s_tot, s_tot2;
    int t = threadIdx.x, lane = t & 63, wid = t >> 6;
    int run = 0, run2 = 0;
    for (int base = 0; base < N_NODES; base += 8192) {
        int i0 = base + t * 8;
        int v[8], pre[8], gpre[8];
        int s = 0, gs = 0;
        #pragma unroll
        for (int j = 0; j < 8; j++) {
            int i = i0 + j;
            v[j] = (i < N_NODES) ? cnt[i] : 0;
            pre[j] = s;  s += v[j];
            gpre[j] = gs; gs += (v[j] + 15) >> 4;
        }
        int tsum = s, gsum = gs;
        int sc = tsum, sc2 = gsum;
        #pragma unroll
        for (int off = 1; off < 64; off <<= 1) {
            int o = __shfl_up(sc, off);
            int o2 = __shfl_up(sc2, off);
            if (lane >= off) { sc += o; sc2 += o2; }
        }
        if (lane == 63) { wsum[wid] = sc; wsum2[wid] = sc2; }
        __syncthreads();
        if (t == 0) {
            int acc2 = 0, acc3 = 0;
            #pragma unroll
            for (int k2 = 0; k2 < 16; k2++) {
                int vv = wsum[k2]; wsum[k2] = acc2; acc2 += vv;
                int v2 = wsum2[k2]; wsum2[k2] = acc3; acc3 += v2;
            }
            s_tot = acc2; s_tot2 = acc3;
        }
        __syncthreads();
        int texcl = run + wsum[wid] + (sc - tsum);
        int gexcl = run2 + wsum2[wid] + (sc2 - gsum);
        #pragma unroll
        for (int j = 0; j < 8; j++) {
            int i = i0 + j;
            if (i < N_NODES) {
                int ex = texcl + pre[j];
                row_start[i] = ex; nxt[i] = ex;
                gstart[i] = gexcl + gpre[j];
            }
        }
        run += s_tot; run2 += s_tot2;
        __syncthreads();
    }
    if (t == 0) { row_start[N_NODES] = run; gstart[N_NODES] = run2; }
}

// ---------------- group list fill: glist[g] = (node, absolute edge base) ------
__global__ __launch_bounds__(256) void k_glist(
    const int* __restrict__ rowst, const int* __restrict__ gstart,
    int2* __restrict__ glist)
{
    int n = blockIdx.x * 256 + threadIdx.x;
    if (n >= N_NODES) return;
    int rs = rowst[n], re = rowst[n + 1];
    int gs = gstart[n];
    int cnt = (re - rs + 15) >> 4;
    for (int k = 0; k < cnt; k++)
        glist[gs + k] = make_int2(n, rs + k * 16);
}

// ---------------- fused: node lin1 (bf16 y) + CSR scatter w/ payload ----------------
__global__ __launch_bounds__(256) void k_lin1_scatter(
    const void* __restrict__ x, const void* __restrict__ w1,
    const void* __restrict__ b1, u16* __restrict__ y,
    const int* __restrict__ dst, const int* __restrict__ srcp,
    const void* __restrict__ ea, int* __restrict__ nxt,
    int2* __restrict__ csr, const int* __restrict__ flag)
{
    __shared__ float sx[2][64];
    int fl = getflag(flag);
    int t = threadIdx.x;
    if (blockIdx.x >= 782) {   // scatter
        int e = (blockIdx.x - 782) * 256 + t;
        if (e < N_EDGES) {
            int p = atomicAdd(&nxt[dst[e]], 1);
            int2 v;
            v.x = srcp[e];
            v.y = __float_as_int(ldf(ea, e, fl));
            csr[p] = v;
        }
        return;
    }
    // lin1
    int col = t & 127, half = t >> 7;
    float wreg[64];
    #pragma unroll
    for (int k = 0; k < 64; k++) wreg[k] = ldf(w1, k * 128 + col, fl);
    float bias = ldf(b1, col, fl);
    int base = blockIdx.x * 64;
    for (int it = 0; it < 32; ++it) {
        __syncthreads();
        if (t < 128) {
            int nh = base + it * 2 + (t >> 6);
            sx[t >> 6][t & 63] = (nh < N_NODES) ? ldf(x, nh * 64 + (t & 63), fl) : 0.f;
        }
        __syncthreads();
        float acc = bias;
        #pragma unroll
        for (int k = 0; k < 64; k++) acc = fmaf(sx[half][k], wreg[k], acc);
        int n = base + it * 2 + half;
        if (n < N_NODES) y[(size_t)n * 128 + col] = f2bf(acc);
    }
}

// ---------------- R13 embed: wave per group, 512-thread blocks + idle skip ----
// R12 post-mortem: 1024-thread blocks REGRESSED (141->147.5us, Occ 42->38%) --
// amortization knee is at 512; coarser block granularity costs more than the
// halved preamble saves. R13 = R11 exactly (best verified: 141us, 740.5 total)
// + the one decoupled good piece of R12: blocks fully past ng (~29% of the
// 12110-block overlaunch, actual ng ~69k vs NG_MAX 96875) skip the 34.8KB
// staging entirely (block-uniform test BEFORE any barrier).
// Body single-shot, no loop-carried state (R5/R10 rule).
__global__ __launch_bounds__(512) void k_embed_grp(
    const u16* __restrict__ y, const int2* __restrict__ csr,
    const int* __restrict__ rowst, const int* __restrict__ gstart,
    const int2* __restrict__ glist,
    const u16* __restrict__ gt, const u32* __restrict__ w1pk,
    const float* __restrict__ csum, const float* __restrict__ bwp,
    float* __restrict__ h1stage, float* __restrict__ vacc)
{
    __shared__ u16 sB[128 * 136];
    __shared__ u32 sW1[64];
    __shared__ float sCSf[128];
    __shared__ float sBWf[128];
    int ng = gstart[N_NODES];
    if (blockIdx.x * 8 >= ng) return;      // fully idle block: skip staging (uniform)
    int t = threadIdx.x;
    for (int c = t; c < 128 * 32; c += 512) {
        int row = c >> 5, ch = c & 31;
        *(ushort4*)&sB[row * 136 + ch * 4] = *(const ushort4*)&gt[row * 128 + ch * 4];
    }
    if (t < 64) sW1[t] = w1pk[t];
    if (t < 128) sCSf[t] = csum[t];
    else if (t < 256) sBWf[t - 128] = bwp[t - 128];
    int l = t & 63, w = t >> 6;            // w in [0,8)
    int m = l & 15, q = l >> 4;
    __syncthreads();                       // all threads reach barrier first
    int gid = blockIdx.x * 8 + w;
    if (gid >= ng) return;                 // overlaunched waves exit after barrier
    int2 ge = glist[gid];
    int node = ge.x, base = ge.y;
    int re = rowst[node + 1];
    int row = base + m;
    if (row >= re) row = re - 1;           // pad lanes masked via rs2=0 below
    int2 sa = csr[row];
    float av = __int_as_float(sa.y);
    const u16* yr = y + (size_t)sa.x * 128 + q * 8;

    // unpack + relu + LN1 stats
    bf16x8 efrag[4];
    float s1 = 0.f, s2 = 0.f;
    #pragma unroll
    for (int kb = 0; kb < 4; kb++) {
        u32x4 yu = __builtin_bit_cast(u32x4, *(const bf16x8*)(yr + kb * 32));
        u32x4 wv4 = *(const u32x4*)&sW1[kb * 16 + q * 4];
        u32x4 ep;
        #pragma unroll
        for (int j2 = 0; j2 < 4; j2++) {
            u32 yw = yu[j2];
            u32 ww = wv4[j2];
            float y0 = __uint_as_float(yw << 16);
            float y1 = __uint_as_float(yw & 0xffff0000u);
            float w0 = __uint_as_float(ww << 16);
            float w1v = __uint_as_float(ww & 0xffff0000u);
            float u0 = fmaxf(fmaf(av, w0, y0), 0.f);
            float u1 = fmaxf(fmaf(av, w1v, y1), 0.f);
            s1 += u0; s2 = fmaf(u0, u0, s2);
            s1 += u1; s2 = fmaf(u1, u1, s2);
            ep[j2] = __builtin_amdgcn_perm(__float_as_uint(u1),
                                           __float_as_uint(u0), 0x07060302u);
        }
        efrag[kb] = __builtin_bit_cast(bf16x8, ep);
    }
    s1 += __shfl_xor(s1, 16); s2 += __shfl_xor(s2, 16);
    s1 += __shfl_xor(s1, 32); s2 += __shfl_xor(s2, 32);
    float mu = s1 * (1.f / 128.f);
    float alpha = rsqrtf(s2 * (1.f / 128.f) - mu * mu + 1e-5f);
    float beta = -mu * alpha;

    f32x4 zf = {0.f, 0.f, 0.f, 0.f};
    f32x4 acc[8];
    #pragma unroll
    for (int nb = 0; nb < 8; nb++) acc[nb] = zf;
    #pragma unroll
    for (int nb = 0; nb < 8; nb++) {
        const u16* grow = &sB[(nb * 16 + m) * 136 + q * 8];
        #pragma unroll
        for (int kb = 0; kb < 4; kb++) {
            bf16x8 gfrag = *(const bf16x8*)(grow + kb * 32);
            acc[nb] = __builtin_amdgcn_mfma_f32_16x16x32_bf16(gfrag, efrag[kb], acc[nb], 0, 0, 0);
        }
    }
    float t1 = 0.f, t2 = 0.f;
    #pragma unroll
    for (int nb = 0; nb < 8; nb++) {
        float4 cs4 = *(const float4*)&sCSf[nb * 16 + q * 4];
        float4 bw4 = *(const float4*)&sBWf[nb * 16 + q * 4];
        float csa[4] = {cs4.x, cs4.y, cs4.z, cs4.w};
        float bwa[4] = {bw4.x, bw4.y, bw4.z, bw4.w};
        #pragma unroll
        for (int r = 0; r < 4; r++) {
            float z = fmaxf(fmaf(alpha, acc[nb][r], fmaf(beta, csa[r], bwa[r])), 0.f);
            acc[nb][r] = z;
            t1 += z; t2 = fmaf(z, z, t2);
        }
    }
    t1 += __shfl_xor(t1, 16); t2 += __shfl_xor(t2, 16);
    t1 += __shfl_xor(t1, 32); t2 += __shfl_xor(t2, 32);
    float mu2 = t1 * (1.f / 128.f);
    float rs2 = rsqrtf(t2 * (1.f / 128.f) - mu2 * mu2 + 1e-5f);
    if (base + m >= re) rs2 = 0.f;         // mask pad edges (lane's edge = m)
    float Vc = rs2 * mu2;

    // tree-reduce acc*rs2 over the 16 edge columns
    bool sel0 = (m & 1), sel1 = (m & 2), sel2 = (m & 4), sel3 = (m & 8);
    float sacc0, sacc1;
    {
        float s16v[16];
        #pragma unroll
        for (int k = 0; k < 16; k++) {
            int nb = k >> 1, rh = (k & 1) << 1;
            float a = acc[nb][rh] * rs2, b = acc[nb][rh + 1] * rs2;
            float keep = sel0 ? b : a;
            float send = sel0 ? a : b;
            s16v[k] = keep + __shfl_xor(send, 1);
        }
        float s8v[8];
        #pragma unroll
        for (int nb = 0; nb < 8; nb++) {
            float a = s16v[nb * 2], b = s16v[nb * 2 + 1];
            float keep = sel1 ? b : a;
            float send = sel1 ? a : b;
            s8v[nb] = keep + __shfl_xor(send, 2);
        }
        float s4v[4];
        #pragma unroll
        for (int k = 0; k < 4; k++) {
            float a = s8v[k * 2], b = s8v[k * 2 + 1];
            float keep = sel2 ? b : a;
            float send = sel2 ? a : b;
            s4v[k] = keep + __shfl_xor(send, 4);
        }
        float a0 = s4v[0], b0 = s4v[1];
        float keep0 = sel3 ? b0 : a0, send0 = sel3 ? a0 : b0;
        sacc0 = keep0 + __shfl_xor(send0, 8);
        float a1 = s4v[2], b1 = s4v[3];
        float keep1 = sel3 ? b1 : a1, send1 = sel3 ? a1 : b1;
        sacc1 = keep1 + __shfl_xor(send1, 8);
    }
    // V reduce over the 16 edges (m dim)
    Vc += __shfl_xor(Vc, 1); Vc += __shfl_xor(Vc, 2);
    Vc += __shfl_xor(Vc, 4); Vc += __shfl_xor(Vc, 8);
    if (l == 0) unsafeAtomicAdd(&vacc[node], Vc);
    #pragma unroll
    for (int k = 0; k < 2; k++) {
        int nb = (k << 2) | (((m >> 3) & 1) << 1) | ((m >> 2) & 1);
        int f = nb * 16 + q * 4 + (m & 3);
        float sv = (k == 0) ? sacc0 : sacc1;
        unsafeAtomicAdd(&h1stage[(size_t)node * 128 + f], sv);
    }
}

// ---------------- embed finalize: h1 = bf16(g*(S - V) + d*b) ----------------
__global__ __launch_bounds__(256) void k_embed_fin(
    const float* __restrict__ h1stage, const float* __restrict__ vacc,
    const int* __restrict__ rowst,
    const void* __restrict__ lng, const void* __restrict__ lnb,
    u16* __restrict__ h1, const int* __restrict__ flag)
{
    int fl = getflag(flag);
    int idx = blockIdx.x * 256 + threadIdx.x;   // 6250 blocks * 256 = 50000*32
    int node = idx >> 5;
    int f4 = (idx & 31) * 4;
    float4 sv = *(const float4*)&h1stage[(size_t)node * 128 + f4];
    float V = vacc[node];
    float dg = (float)(rowst[node + 1] - rowst[node]);
    ushort4 o;
    o.x = f2bf(fmaf(ldf(lng, f4 + 0, fl), sv.x - V, dg * ldf(lnb, f4 + 0, fl)));
    o.y = f2bf(fmaf(ldf(lng, f4 + 1, fl), sv.y - V, dg * ldf(lnb, f4 + 1, fl)));
    o.z = f2bf(fmaf(ldf(lng, f4 + 2, fl), sv.z - V, dg * ldf(lnb, f4 + 2, fl)));
    o.w = f2bf(fmaf(ldf(lng, f4 + 3, fl), sv.w - V, dg * ldf(lnb, f4 + 3, fl)));
    *(ushort4*)&h1[(size_t)node * 128 + f4] = o;
}

// ---------------- fused q/k/v/skip projection GEMM (bf16 h input) ----------------
__global__ __launch_bounds__(256) void k_proj(
    const u16* __restrict__ hin, const u16* __restrict__ wt,
    const float* __restrict__ bcat, u16* __restrict__ outp)
{
    __shared__ u16 sA[64 * 136];
    __shared__ u16 sB[128 * 136];
    int t = threadIdx.x;
    int l = t & 63, w = t >> 6;
    int m = l & 15, q = l >> 4;
    int rowbase = blockIdx.x * 64;
    for (int c = t; c < 64 * 32; c += 256) {
        int row = c >> 5, ch = c & 31;
        int gr = rowbase + row;
        ushort4 pk = make_ushort4(0, 0, 0, 0);
        if (gr < N_NODES) pk = *(const ushort4*)&hin[(size_t)gr * 128 + ch * 4];
        *(ushort4*)&sA[row * 136 + ch * 4] = pk;
    }
    __syncthreads();
    bf16x8 afrag[4];
    #pragma unroll
    for (int kb = 0; kb < 4; kb++)
        afrag[kb] = *(const bf16x8*)&sA[(w * 16 + m) * 136 + kb * 32 + q * 8];

    f32x4 zf = {0.f, 0.f, 0.f, 0.f};
    for (int g = 0; g < 4; ++g) {
        __syncthreads();
        for (int c = t; c < 128 * 32; c += 256) {
            int row = c >> 5, ch = c & 31;
            *(ushort4*)&sB[row * 136 + ch * 4] = *(const ushort4*)&wt[(g * 128 + row) * 128 + ch * 4];
        }
        __syncthreads();
        f32x4 acc[8];
        #pragma unroll
        for (int nb = 0; nb < 8; nb++) acc[nb] = zf;
        #pragma unroll
        for (int nb = 0; nb < 8; nb++) {
            const u16* brow = &sB[(nb * 16 + m) * 136 + q * 8];
            #pragma unroll
            for (int kb = 0; kb < 4; kb++) {
                bf16x8 bfrag = *(const bf16x8*)(brow + kb * 32);
                acc[nb] = __builtin_amdgcn_mfma_f32_16x16x32_bf16(afrag[kb], bfrag, acc[nb], 0, 0, 0);
            }
        }
        #pragma unroll
        for (int nb = 0; nb < 8; nb++) {
            int col = g * 128 + nb * 16 + m;
            float bb = bcat[col];
            #pragma unroll
            for (int r = 0; r < 4; r++) {
                int row = rowbase + w * 16 + q * 4 + r;
                if (row < N_NODES) outp[(size_t)row * 512 + col] = f2bf(acc[nb][r] + bb);
            }
        }
    }
}

// ---------------- attention: wave per dst node, 4 subs x 16 lanes, no-max exp ----------------
__global__ __launch_bounds__(256) void k_attn(
    const u16* __restrict__ qkvs,
    const int* __restrict__ rowst, const int2* __restrict__ csr,
    const void* __restrict__ wep, u16* __restrict__ hout,
    const int* __restrict__ flag)
{
    int fl = getflag(flag);
    int t = threadIdx.x;
    int l = t & 63, w = t >> 6;
    int dstn = blockIdx.x * 4 + w;        // grid*4 == N exactly
    int lane16 = l & 15, sub = l >> 4;
    int f0 = lane16 * 8;                  // 8 features per lane
    const float scale = 0.17677669529663687f;  // 1/sqrt(32)

    bf16x8 q8 = *(const bf16x8*)&qkvs[(size_t)dstn * 512 + f0];
    float qf[8], wef[8];
    if (fl) {                              // vectorized wep load (wave-uniform branch)
        float4 w0 = *(const float4*)((const float*)wep + f0);
        float4 w1v = *(const float4*)((const float*)wep + f0 + 4);
        wef[0] = w0.x; wef[1] = w0.y; wef[2] = w0.z; wef[3] = w0.w;
        wef[4] = w1v.x; wef[5] = w1v.y; wef[6] = w1v.z; wef[7] = w1v.w;
    } else {
        bf16x8 w8 = *(const bf16x8*)((const u16*)wep + f0);
        #pragma unroll
        for (int j = 0; j < 8; j++) wef[j] = bf2f((u16)w8[j]);
    }
    #pragma unroll
    for (int j = 0; j < 8; j++) qf[j] = bf2f((u16)q8[j]) * scale;

    float si = 0.f;
    float a8[8];
    #pragma unroll
    for (int j = 0; j < 8; j++) a8[j] = 0.f;

    int rs = rowst[dstn], re = rowst[dstn + 1];
    int i = rs + sub;
    for (; i + 4 < re; i += 8) {
        int2 sa = csr[i];
        int2 sb = csr[i + 4];
        float ava = __int_as_float(sa.y);
        float avb = __int_as_float(sb.y);
        const u16* sra = &qkvs[(size_t)sa.x * 512 + f0];
        const u16* srb = &qkvs[(size_t)sb.x * 512 + f0];
        bf16x8 k8a = *(const bf16x8*)(sra + 128);
        bf16x8 v8a = *(const bf16x8*)(sra + 256);
        bf16x8 k8b = *(const bf16x8*)(srb + 128);
        bf16x8 v8b = *(const bf16x8*)(srb + 256);
        float pa = 0.f, pb = 0.f;
        float vea[8], veb[8];
        #pragma unroll
        for (int j = 0; j < 8; j++) {
            pa = fmaf(qf[j], fmaf(ava, wef[j], bf2f((u16)k8a[j])), pa);
            pb = fmaf(qf[j], fmaf(avb, wef[j], bf2f((u16)k8b[j])), pb);
            vea[j] = fmaf(ava, wef[j], bf2f((u16)v8a[j]));
            veb[j] = fmaf(avb, wef[j], bf2f((u16)v8b[j]));
        }
        pa += __shfl_xor(pa, 1); pb += __shfl_xor(pb, 1);
        pa += __shfl_xor(pa, 2); pb += __shfl_xor(pb, 2);
        float pea = __expf(pa);
        float peb = __expf(pb);
        si += pea + peb;
        #pragma unroll
        for (int j = 0; j < 8; j++)
            a8[j] = fmaf(pea, vea[j], fmaf(peb, veb[j], a8[j]));
    }
    if (i < re) {   // tail single edge
        int2 sa = csr[i];
        float av = __int_as_float(sa.y);
        const u16* sr = &qkvs[(size_t)sa.x * 512 + f0];
        bf16x8 k8 = *(const bf16x8*)(sr + 128);
        bf16x8 v8 = *(const bf16x8*)(sr + 256);
        float p = 0.f;
        float ve[8];
        #pragma unroll
        for (int j = 0; j < 8; j++) {
            p = fmaf(qf[j], fmaf(av, wef[j], bf2f((u16)k8[j])), p);
            ve[j] = fmaf(av, wef[j], bf2f((u16)v8[j]));
        }
        p += __shfl_xor(p, 1); p += __shfl_xor(p, 2);
        float pe = __expf(p);
        si += pe;
        #pragma unroll
        for (int j = 0; j < 8; j++) a8[j] = fmaf(pe, ve[j], a8[j]);
    }
    #pragma unroll
    for (int off = 16; off < 64; off <<= 1) {
        si += __shfl_xor(si, off);
        #pragma unroll
        for (int j = 0; j < 8; j++) a8[j] += __shfl_xor(a8[j], off);
    }
    if (sub == 0) {
        float inv = 1.f / (si + 1e-16f);
        bf16x8 s8 = *(const bf16x8*)&qkvs[(size_t)dstn * 512 + 384 + f0];
        ushort4 p0, p1;
        float o[8];
        #pragma unroll
        for (int j = 0; j < 8; j++)
            o[j] = fmaxf(fmaf(a8[j], inv, bf2f((u16)s8[j])), 0.f);
        p0.x = f2bf(o[0]); p0.y = f2bf(o[1]); p0.z = f2bf(o[2]); p0.w = f2bf(o[3]);
        p1.x = f2bf(o[4]); p1.y = f2bf(o[5]); p1.z = f2bf(o[6]); p1.w = f2bf(o[7]);
        u16* hr = hout + (size_t)dstn * 128 + f0;
        *(ushort4*)hr = p0;
        *(ushort4*)(hr + 4) = p1;
    }
}

// ---------------- global mean pool (bf16 h input, u32 feature pairs) ----------------
__global__ __launch_bounds__(256) void k_pool(
    const u16* __restrict__ h, const int* __restrict__ batch,
    float* __restrict__ gsum, float* __restrict__ gcnt)
{
    __shared__ float ssum[8 * 128];
    __shared__ float scnt[8];
    int t = threadIdx.x;
    for (int i = t; i < 8 * 128; i += 256) ssum[i] = 0.f;
    if (t < 8) scnt[t] = 0.f;
    __syncthreads();
    int f2 = (t & 63) * 2, quarter = t >> 6;
    int per = (N_NODES + gridDim.x - 1) / gridDim.x;
    int lo = blockIdx.x * per;
    int hi = lo + per; if (hi > N_NODES) hi = N_NODES;
    float r0 = 0.f, r1 = 0.f, rcnt = 0.f; int rg = -1;
    for (int n = lo + quarter; n < hi; n += 4) {
        int g = batch[n];
        if (g != rg) {
            if (rg >= 0) {
                atomicAdd(&ssum[rg * 128 + f2], r0);
                atomicAdd(&ssum[rg * 128 + f2 + 1], r1);
                if (f2 == 0) atomicAdd(&scnt[rg], rcnt);
            }
            rg = g; r0 = 0.f; r1 = 0.f; rcnt = 0.f;
        }
        u32 hv = *(const u32*)&h[(size_t)n * 128 + f2];
        r0 += bf2f((u16)(hv & 0xffff));
        r1 += bf2f((u16)(hv >> 16));
        rcnt += 1.f;
    }
    if (rg >= 0) {
        atomicAdd(&ssum[rg * 128 + f2], r0);
        atomicAdd(&ssum[rg * 128 + f2 + 1], r1);
        if (f2 == 0) atomicAdd(&scnt[rg], rcnt);
    }
    __syncthreads();
    for (int i = t; i < 8 * 128; i += 256) unsafeAtomicAdd(&gsum[i], ssum[i]);
    if (t < 8) unsafeAtomicAdd(&gcnt[t], scnt[t]);
}

__global__ void k_out(const float* __restrict__ gsum, const float* __restrict__ gcnt,
                      void* __restrict__ outp, const int* __restrict__ flag) {
    int fl = getflag(flag);
    int t = threadIdx.x;  // 1024
    float c = fmaxf(gcnt[t >> 7], 1.f);
    float v = gsum[t] / c;
    if (fl) ((float*)outp)[t] = v;
    else ((u16*)outp)[t] = f2bf(v);
}

extern "C" void kernel_launch(void* const* d_in, const int* in_sizes, int n_in,
                              void* d_out, int out_size, void* d_ws, size_t ws_size,
                              hipStream_t stream)
{
    (void)in_sizes; (void)n_in; (void)out_size; (void)ws_size;
    const void* x    = d_in[0];
    const int* ei    = (const int*)d_in[1];
    const void* ea   = d_in[2];
    const int* batch = (const int*)d_in[3];
    const void* w1   = d_in[4];
    const void* b1   = d_in[5];
    const void* lng  = d_in[6];
    const void* lnb  = d_in[7];
    const void* w2   = d_in[8];
    const void* b2   = d_in[9];
    const int* srcp = ei;
    const int* dstp = ei + N_EDGES;

    char* wsb = (char*)d_ws;
    size_t cur = 0;
    auto alloc = [&](size_t sz) -> void* {
        void* p = wsb + cur;
        cur += (sz + 255) & ~(size_t)255;
        return p;
    };
    u16*   y      = (u16*)  alloc((size_t)N_NODES * 128 * 2);
    u16*   h1     = (u16*)  alloc((size_t)N_NODES * 128 * 2);   // reused as h3
    u16*   h2     = (u16*)  alloc((size_t)N_NODES * 128 * 2);
    u16*   qkvs   = (u16*)  alloc((size_t)N_NODES * 512 * 2);
    int2*  csr    = (int2*) alloc((size_t)N_EDGES * 8);
    u16*   gt     = (u16*)  alloc(128 * 128 * 2);
    u16*   wcat1  = (u16*)  alloc(512 * 128 * 2);
    u16*   wcat2  = (u16*)  alloc(512 * 128 * 2);
    float* csum   = (float*)alloc(128 * 4);
    float* bwp    = (float*)alloc(128 * 4);
    u32*   w1pk   = (u32*)  alloc(64 * 4);
    float* bcat1  = (float*)alloc(512 * 4);
    float* bcat2  = (float*)alloc(512 * 4);
    int*   cntdeg = (int*)  alloc((size_t)N_NODES * 4);
    int*   rowst  = (int*)  alloc((size_t)(N_NODES + 1) * 4);
    int*   nxt    = (int*)  alloc((size_t)N_NODES * 4);
    float* gsum   = (float*)alloc((8 * 128 + 8) * 4);
    int*   dtflag = (int*)  alloc(256);
    // group-embed buffers (~26.8 MB total)
    float* h1stage = (float*)alloc((size_t)N_NODES * 128 * 4);
    float* vacc    = (float*)alloc((size_t)N_NODES * 4);
    int*   gstart  = (int*)  alloc((size_t)(N_NODES + 1) * 4);
    int2*  glist   = (int2*) alloc((size_t)NG_MAX * 8);
    u16*   h3 = h1;   // h1 is dead after first k_proj

    hipMemsetAsync(cntdeg, 0, (size_t)N_NODES * 4, stream);
    hipMemsetAsync(gsum, 0, (8 * 128 + 8) * 4, stream);
    hipMemsetAsync(h1stage, 0, (size_t)N_NODES * 128 * 4 + 256 + (size_t)N_NODES * 4, stream);

    P8 pw; P8 pb;
    pw.s[0] = d_in[10]; pw.s[1] = d_in[12]; pw.s[2] = d_in[14]; pw.s[3] = d_in[17];
    pw.s[4] = d_in[19]; pw.s[5] = d_in[21]; pw.s[6] = d_in[23]; pw.s[7] = d_in[26];
    pb.s[0] = d_in[11]; pb.s[1] = d_in[13]; pb.s[2] = d_in[15]; pb.s[3] = d_in[18];
    pb.s[4] = d_in[20]; pb.s[5] = d_in[22]; pb.s[6] = d_in[24]; pb.s[7] = d_in[27];

    k_deg_detect<<<3126, 256, 0, stream>>>(dstp, cntdeg, (const u16*)x, dtflag);
    k_prep_all<<<517, 256, 0, stream>>>(pw, pb, wcat1, wcat2, bcat1, bcat2,
                                        w2, lng, lnb, b2, w1, gt, csum, bwp, w1pk, dtflag);
    k_scan<<<1, 1024, 0, stream>>>(cntdeg, rowst, nxt, gstart);
    k_glist<<<196, 256, 0, stream>>>(rowst, gstart, glist);
    k_lin1_scatter<<<3907, 256, 0, stream>>>(x, w1, b1, y, dstp, srcp, ea, nxt, csr, dtflag);
    k_embed_grp<<<(NG_MAX + 7) / 8, 512, 0, stream>>>(y, csr, rowst, gstart, glist,
                                                      gt, w1pk, csum, bwp, h1stage, vacc);
    k_embed_fin<<<6250, 256, 0, stream>>>(h1stage, vacc, rowst, lng, lnb, h1, dtflag);
    k_proj<<<782, 256, 0, stream>>>(h1, wcat1, bcat1, qkvs);
    k_attn<<<12500, 256, 0, stream>>>(qkvs, rowst, csr, d_in[16], h2, dtflag);
    k_proj<<<782, 256, 0, stream>>>(h2, wcat2, bcat2, qkvs);
    k_attn<<<12500, 256, 0, stream>>>(qkvs, rowst, csr, d_in[25], h3, dtflag);
    k_pool<<<128, 256, 0, stream>>>(h3, batch, gsum, gsum + 8 * 128);
    k_out<<<1, 1024, 0, stream>>>(gsum, gsum + 8 * 128, d_out, dtflag);
}

// Round 15
// 721.721 us; speedup vs baseline: 1.0401x; 1.0089x over previous
//
#include <hip/hip_runtime.h>

typedef unsigned short u16;
typedef unsigned int u32;
typedef __attribute__((ext_vector_type(8))) short bf16x8;
typedef __attribute__((ext_vector_type(4))) float f32x4;
typedef __attribute__((ext_vector_type(4))) u32 u32x4;

#define N_NODES 50000
#define N_EDGES 800000
#define NG_MAX ((N_EDGES + 15 * N_NODES) / 16)   // 96875 group upper bound

__device__ __forceinline__ float bf2f(u16 u) {
    union { u32 i; float f; } v; v.i = ((u32)u) << 16; return v.f;
}
__device__ __forceinline__ u16 f2bf(float f) {
    union { u32 i; float f; } v; v.f = f;
    u32 i = v.i;
    return (u16)((i + 0x7FFFu + ((i >> 16) & 1u)) >> 16);
}
// dtype-agnostic load: fl!=0 -> float32 buffer, else bf16 (u16) buffer
__device__ __forceinline__ float ldf(const void* p, int i, int fl) {
    return fl ? ((const float*)p)[i] : bf2f(((const u16*)p)[i]);
}
__device__ __forceinline__ int getflag(const int* flag) {
    return __builtin_amdgcn_readfirstlane(*flag);
}

struct P8 { const void* s[8]; };

// ---------------- fused: edge-degree histogram + dtype detection ----------------
__global__ __launch_bounds__(256) void k_deg_detect(
    const int* __restrict__ dst, int* __restrict__ cnt,
    const u16* __restrict__ xr, int* __restrict__ flag)
{
    int t = threadIdx.x;
    if (blockIdx.x < 3125) {
        int e = blockIdx.x * 256 + t;
        atomicAdd(&cnt[dst[e]], 1);   // 3125*256 == N_EDGES exactly
        return;
    }
    // block 3125: dtype detect on x[0..4095]
    __shared__ int sc[256];
    int c = 0;
    for (int i = t; i < 4096; i += 256) {
        u32 e = (xr[i] >> 7) & 0xFF;
        if (e >= 143) c++;
    }
    sc[t] = c;
    __syncthreads();
    for (int s = 128; s > 0; s >>= 1) {
        if (t < s) sc[t] += sc[t + s];
        __syncthreads();
    }
    if (t == 0) *flag = (sc[0] > 64) ? 1 : 0;   // 1 = float32, 0 = bf16
}

// ---------------- fused weight prep: transposes + bias concat + W2 folding ----------------
__global__ __launch_bounds__(256) void k_prep_all(
    P8 pw, P8 pb, u16* __restrict__ wcat1, u16* __restrict__ wcat2,
    float* __restrict__ bcat1, float* __restrict__ bcat2,
    const void* __restrict__ w2, const void* __restrict__ lng_,
    const void* __restrict__ lnb_, const void* __restrict__ b2_,
    const void* __restrict__ w1, u16* __restrict__ gt,
    float* __restrict__ csum, float* __restrict__ bwp,
    u32* __restrict__ w1pk, const int* __restrict__ flag)
{
    int fl = getflag(flag);
    int b = blockIdx.x, t = threadIdx.x;
    if (b < 512) {          // 8 x 128x128 weight transposes
        int gid = b * 256 + t;
        int wi = gid >> 14;
        int id = gid & 16383;
        int k = id >> 7, n = id & 127;
        u16* d = (wi < 4) ? (wcat1 + wi * 16384) : (wcat2 + (wi - 4) * 16384);
        d[n * 128 + k] = f2bf(ldf(pw.s[wi], id, fl));
    } else if (b < 516) {   // bias concat
        int tt = (b - 512) * 256 + t;
        float v = ldf(pb.s[tt >> 7], tt & 127, fl);
        if (tt < 512) bcat1[tt] = v; else bcat2[tt - 512] = v;
    } else {                // W2 folding (t = output column)
        if (t < 128) {
            float cs = 0.f, bw = 0.f;
            for (int f = 0; f < 128; f++) {
                float wv = ldf(w2, f * 128 + t, fl);
                float g = ldf(lng_, f, fl);
                float bb = ldf(lnb_, f, fl);
                u16 gwq = f2bf(g * wv);
                gt[t * 128 + f] = gwq;
                cs += bf2f(gwq);
                bw = fmaf(bb, wv, bw);
            }
            csum[t] = cs;
            bwp[t] = bw + ldf(b2_, t, fl);
            if (t < 64)
                w1pk[t] = (u32)f2bf(ldf(w1, 64 * 128 + t * 2, fl)) |
                          ((u32)f2bf(ldf(w1, 64 * 128 + t * 2 + 1, fl)) << 16);
        }
    }
}

// ---------------- CSR scan + group scan (single block, 1024 threads) ----------------
__global__ __launch_bounds__(1024) void k_scan(const int* __restrict__ cnt,
                                               int* __restrict__ row_start,
                                               int* __restrict__ nxt,
                                               int* __restrict__ gstart)
{
    __shared__ int wsum[16];
    __shared__ int wsum2[16];
    __shared__ int s_tot, s_tot2;
    int t = threadIdx.x, lane = t & 63, wid = t >> 6;
    int run = 0, run2 = 0;
    for (int base = 0; base < N_NODES; base += 8192) {
        int i0 = base + t * 8;
        int v[8], pre[8], gpre[8];
        int s = 0, gs = 0;
        #pragma unroll
        for (int j = 0; j < 8; j++) {
            int i = i0 + j;
            v[j] = (i < N_NODES) ? cnt[i] : 0;
            pre[j] = s;  s += v[j];
            gpre[j] = gs; gs += (v[j] + 15) >> 4;
        }
        int tsum = s, gsum = gs;
        int sc = tsum, sc2 = gsum;
        #pragma unroll
        for (int off = 1; off < 64; off <<= 1) {
            int o = __shfl_up(sc, off);
            int o2 = __shfl_up(sc2, off);
            if (lane >= off) { sc += o; sc2 += o2; }
        }
        if (lane == 63) { wsum[wid] = sc; wsum2[wid] = sc2; }
        __syncthreads();
        if (t == 0) {
            int acc2 = 0, acc3 = 0;
            #pragma unroll
            for (int k2 = 0; k2 < 16; k2++) {
                int vv = wsum[k2]; wsum[k2] = acc2; acc2 += vv;
                int v2 = wsum2[k2]; wsum2[k2] = acc3; acc3 += v2;
            }
            s_tot = acc2; s_tot2 = acc3;
        }
        __syncthreads();
        int texcl = run + wsum[wid] + (sc - tsum);
        int gexcl = run2 + wsum2[wid] + (sc2 - gsum);
        #pragma unroll
        for (int j = 0; j < 8; j++) {
            int i = i0 + j;
            if (i < N_NODES) {
                int ex = texcl + pre[j];
                row_start[i] = ex; nxt[i] = ex;
                gstart[i] = gexcl + gpre[j];
            }
        }
        run += s_tot; run2 += s_tot2;
        __syncthreads();
    }
    if (t == 0) { row_start[N_NODES] = run; gstart[N_NODES] = run2; }
}

// ---------------- group list fill: glist[g] = (node, absolute edge base) ------
__global__ __launch_bounds__(256) void k_glist(
    const int* __restrict__ rowst, const int* __restrict__ gstart,
    int2* __restrict__ glist)
{
    int n = blockIdx.x * 256 + threadIdx.x;
    if (n >= N_NODES) return;
    int rs = rowst[n], re = rowst[n + 1];
    int gs = gstart[n];
    int cnt = (re - rs + 15) >> 4;
    for (int k = 0; k < cnt; k++)
        glist[gs + k] = make_int2(n, rs + k * 16);
}

// ---------------- fused: node lin1 (bf16 y) + CSR scatter w/ payload ----------------
__global__ __launch_bounds__(256) void k_lin1_scatter(
    const void* __restrict__ x, const void* __restrict__ w1,
    const void* __restrict__ b1, u16* __restrict__ y,
    const int* __restrict__ dst, const int* __restrict__ srcp,
    const void* __restrict__ ea, int* __restrict__ nxt,
    int2* __restrict__ csr, const int* __restrict__ flag)
{
    __shared__ float sx[2][64];
    int fl = getflag(flag);
    int t = threadIdx.x;
    if (blockIdx.x >= 782) {   // scatter
        int e = (blockIdx.x - 782) * 256 + t;
        if (e < N_EDGES) {
            int p = atomicAdd(&nxt[dst[e]], 1);
            int2 v;
            v.x = srcp[e];
            v.y = __float_as_int(ldf(ea, e, fl));
            csr[p] = v;
        }
        return;
    }
    // lin1
    int col = t & 127, half = t >> 7;
    float wreg[64];
    #pragma unroll
    for (int k = 0; k < 64; k++) wreg[k] = ldf(w1, k * 128 + col, fl);
    float bias = ldf(b1, col, fl);
    int base = blockIdx.x * 64;
    for (int it = 0; it < 32; ++it) {
        __syncthreads();
        if (t < 128) {
            int nh = base + it * 2 + (t >> 6);
            sx[t >> 6][t & 63] = (nh < N_NODES) ? ldf(x, nh * 64 + (t & 63), fl) : 0.f;
        }
        __syncthreads();
        float acc = bias;
        #pragma unroll
        for (int k = 0; k < 64; k++) acc = fmaf(sx[half][k], wreg[k], acc);
        int n = base + it * 2 + half;
        if (n < N_NODES) y[(size_t)n * 128 + col] = f2bf(acc);
    }
}

// ---------------- R15 embed: wave per group, 512-thread blocks + idle skip ----
// Verified best structure (R14: 131us, total 728). R15 delta: staging copies
// vectorized ushort4->bf16x8 (16B, 8->4 iters). Body byte-identical
// single-shot (R5/R10 rule: no loop-carried state).
__global__ __launch_bounds__(512) void k_embed_grp(
    const u16* __restrict__ y, const int2* __restrict__ csr,
    const int* __restrict__ rowst, const int* __restrict__ gstart,
    const int2* __restrict__ glist,
    const u16* __restrict__ gt, const u32* __restrict__ w1pk,
    const float* __restrict__ csum, const float* __restrict__ bwp,
    float* __restrict__ h1stage, float* __restrict__ vacc)
{
    __shared__ u16 sB[128 * 136];
    __shared__ u32 sW1[64];
    __shared__ float sCSf[128];
    __shared__ float sBWf[128];
    int ng = gstart[N_NODES];
    if (blockIdx.x * 8 >= ng) return;      // fully idle block: skip staging (uniform)
    int t = threadIdx.x;
    for (int c = t; c < 128 * 16; c += 512) {   // 16B copies: row = c>>4, ch = c&15
        int row = c >> 4, ch = c & 15;
        *(bf16x8*)&sB[row * 136 + ch * 8] = *(const bf16x8*)&gt[row * 128 + ch * 8];
    }
    if (t < 64) sW1[t] = w1pk[t];
    if (t < 128) sCSf[t] = csum[t];
    else if (t < 256) sBWf[t - 128] = bwp[t - 128];
    int l = t & 63, w = t >> 6;            // w in [0,8)
    int m = l & 15, q = l >> 4;
    __syncthreads();                       // all threads reach barrier first
    int gid = blockIdx.x * 8 + w;
    if (gid >= ng) return;                 // overlaunched waves exit after barrier
    int2 ge = glist[gid];
    int node = ge.x, base = ge.y;
    int re = rowst[node + 1];
    int row = base + m;
    if (row >= re) row = re - 1;           // pad lanes masked via rs2=0 below
    int2 sa = csr[row];
    float av = __int_as_float(sa.y);
    const u16* yr = y + (size_t)sa.x * 128 + q * 8;

    // unpack + relu + LN1 stats
    bf16x8 efrag[4];
    float s1 = 0.f, s2 = 0.f;
    #pragma unroll
    for (int kb = 0; kb < 4; kb++) {
        u32x4 yu = __builtin_bit_cast(u32x4, *(const bf16x8*)(yr + kb * 32));
        u32x4 wv4 = *(const u32x4*)&sW1[kb * 16 + q * 4];
        u32x4 ep;
        #pragma unroll
        for (int j2 = 0; j2 < 4; j2++) {
            u32 yw = yu[j2];
            u32 ww = wv4[j2];
            float y0 = __uint_as_float(yw << 16);
            float y1 = __uint_as_float(yw & 0xffff0000u);
            float w0 = __uint_as_float(ww << 16);
            float w1v = __uint_as_float(ww & 0xffff0000u);
            float u0 = fmaxf(fmaf(av, w0, y0), 0.f);
            float u1 = fmaxf(fmaf(av, w1v, y1), 0.f);
            s1 += u0; s2 = fmaf(u0, u0, s2);
            s1 += u1; s2 = fmaf(u1, u1, s2);
            ep[j2] = __builtin_amdgcn_perm(__float_as_uint(u1),
                                           __float_as_uint(u0), 0x07060302u);
        }
        efrag[kb] = __builtin_bit_cast(bf16x8, ep);
    }
    s1 += __shfl_xor(s1, 16); s2 += __shfl_xor(s2, 16);
    s1 += __shfl_xor(s1, 32); s2 += __shfl_xor(s2, 32);
    float mu = s1 * (1.f / 128.f);
    float alpha = rsqrtf(s2 * (1.f / 128.f) - mu * mu + 1e-5f);
    float beta = -mu * alpha;

    f32x4 zf = {0.f, 0.f, 0.f, 0.f};
    f32x4 acc[8];
    #pragma unroll
    for (int nb = 0; nb < 8; nb++) acc[nb] = zf;
    #pragma unroll
    for (int nb = 0; nb < 8; nb++) {
        const u16* grow = &sB[(nb * 16 + m) * 136 + q * 8];
        #pragma unroll
        for (int kb = 0; kb < 4; kb++) {
            bf16x8 gfrag = *(const bf16x8*)(grow + kb * 32);
            acc[nb] = __builtin_amdgcn_mfma_f32_16x16x32_bf16(gfrag, efrag[kb], acc[nb], 0, 0, 0);
        }
    }
    float t1 = 0.f, t2 = 0.f;
    #pragma unroll
    for (int nb = 0; nb < 8; nb++) {
        float4 cs4 = *(const float4*)&sCSf[nb * 16 + q * 4];
        float4 bw4 = *(const float4*)&sBWf[nb * 16 + q * 4];
        float csa[4] = {cs4.x, cs4.y, cs4.z, cs4.w};
        float bwa[4] = {bw4.x, bw4.y, bw4.z, bw4.w};
        #pragma unroll
        for (int r = 0; r < 4; r++) {
            float z = fmaxf(fmaf(alpha, acc[nb][r], fmaf(beta, csa[r], bwa[r])), 0.f);
            acc[nb][r] = z;
            t1 += z; t2 = fmaf(z, z, t2);
        }
    }
    t1 += __shfl_xor(t1, 16); t2 += __shfl_xor(t2, 16);
    t1 += __shfl_xor(t1, 32); t2 += __shfl_xor(t2, 32);
    float mu2 = t1 * (1.f / 128.f);
    float rs2 = rsqrtf(t2 * (1.f / 128.f) - mu2 * mu2 + 1e-5f);
    if (base + m >= re) rs2 = 0.f;         // mask pad edges (lane's edge = m)
    float Vc = rs2 * mu2;

    // tree-reduce acc*rs2 over the 16 edge columns
    bool sel0 = (m & 1), sel1 = (m & 2), sel2 = (m & 4), sel3 = (m & 8);
    float sacc0, sacc1;
    {
        float s16v[16];
        #pragma unroll
        for (int k = 0; k < 16; k++) {
            int nb = k >> 1, rh = (k & 1) << 1;
            float a = acc[nb][rh] * rs2, b = acc[nb][rh + 1] * rs2;
            float keep = sel0 ? b : a;
            float send = sel0 ? a : b;
            s16v[k] = keep + __shfl_xor(send, 1);
        }
        float s8v[8];
        #pragma unroll
        for (int nb = 0; nb < 8; nb++) {
            float a = s16v[nb * 2], b = s16v[nb * 2 + 1];
            float keep = sel1 ? b : a;
            float send = sel1 ? a : b;
            s8v[nb] = keep + __shfl_xor(send, 2);
        }
        float s4v[4];
        #pragma unroll
        for (int k = 0; k < 4; k++) {
            float a = s8v[k * 2], b = s8v[k * 2 + 1];
            float keep = sel2 ? b : a;
            float send = sel2 ? a : b;
            s4v[k] = keep + __shfl_xor(send, 4);
        }
        float a0 = s4v[0], b0 = s4v[1];
        float keep0 = sel3 ? b0 : a0, send0 = sel3 ? a0 : b0;
        sacc0 = keep0 + __shfl_xor(send0, 8);
        float a1 = s4v[2], b1 = s4v[3];
        float keep1 = sel3 ? b1 : a1, send1 = sel3 ? a1 : b1;
        sacc1 = keep1 + __shfl_xor(send1, 8);
    }
    // V reduce over the 16 edges (m dim)
    Vc += __shfl_xor(Vc, 1); Vc += __shfl_xor(Vc, 2);
    Vc += __shfl_xor(Vc, 4); Vc += __shfl_xor(Vc, 8);
    if (l == 0) unsafeAtomicAdd(&vacc[node], Vc);
    #pragma unroll
    for (int k = 0; k < 2; k++) {
        int nb = (k << 2) | (((m >> 3) & 1) << 1) | ((m >> 2) & 1);
        int f = nb * 16 + q * 4 + (m & 3);
        float sv = (k == 0) ? sacc0 : sacc1;
        unsafeAtomicAdd(&h1stage[(size_t)node * 128 + f], sv);
    }
}

// ---------------- R15 proj#1 with FUSED embed-finalize in the sA staging ------
// h1's only consumer was proj#1; apply h1 = bf16(g*(S-V)+d*b) inline while
// staging sA (bit-identical expression to the old k_embed_fin) and delete the
// separate fin kernel (saves ~25MB traffic + one launch). proj#2 unchanged.
__global__ __launch_bounds__(256) void k_proj_fin(
    const float* __restrict__ h1stage, const float* __restrict__ vacc,
    const int* __restrict__ rowst,
    const void* __restrict__ lng, const void* __restrict__ lnb,
    const u16* __restrict__ wt, const float* __restrict__ bcat,
    u16* __restrict__ outp, const int* __restrict__ flag)
{
    __shared__ u16 sA[64 * 136];
    __shared__ u16 sB[128 * 136];
    int fl = getflag(flag);
    int t = threadIdx.x;
    int l = t & 63, w = t >> 6;
    int m = l & 15, q = l >> 4;
    int rowbase = blockIdx.x * 64;
    for (int c = t; c < 64 * 32; c += 256) {
        int row = c >> 5, ch = c & 31;
        int gr = rowbase + row;
        ushort4 pk = make_ushort4(0, 0, 0, 0);
        if (gr < N_NODES) {
            int f4 = ch * 4;
            float4 sv = *(const float4*)&h1stage[(size_t)gr * 128 + f4];
            float V = vacc[gr];
            float dg = (float)(rowst[gr + 1] - rowst[gr]);
            pk.x = f2bf(fmaf(ldf(lng, f4 + 0, fl), sv.x - V, dg * ldf(lnb, f4 + 0, fl)));
            pk.y = f2bf(fmaf(ldf(lng, f4 + 1, fl), sv.y - V, dg * ldf(lnb, f4 + 1, fl)));
            pk.z = f2bf(fmaf(ldf(lng, f4 + 2, fl), sv.z - V, dg * ldf(lnb, f4 + 2, fl)));
            pk.w = f2bf(fmaf(ldf(lng, f4 + 3, fl), sv.w - V, dg * ldf(lnb, f4 + 3, fl)));
        }
        *(ushort4*)&sA[row * 136 + ch * 4] = pk;
    }
    __syncthreads();
    bf16x8 afrag[4];
    #pragma unroll
    for (int kb = 0; kb < 4; kb++)
        afrag[kb] = *(const bf16x8*)&sA[(w * 16 + m) * 136 + kb * 32 + q * 8];

    f32x4 zf = {0.f, 0.f, 0.f, 0.f};
    for (int g = 0; g < 4; ++g) {
        __syncthreads();
        for (int c = t; c < 128 * 32; c += 256) {
            int row = c >> 5, ch = c & 31;
            *(ushort4*)&sB[row * 136 + ch * 4] = *(const ushort4*)&wt[(g * 128 + row) * 128 + ch * 4];
        }
        __syncthreads();
        f32x4 acc[8];
        #pragma unroll
        for (int nb = 0; nb < 8; nb++) acc[nb] = zf;
        #pragma unroll
        for (int nb = 0; nb < 8; nb++) {
            const u16* brow = &sB[(nb * 16 + m) * 136 + q * 8];
            #pragma unroll
            for (int kb = 0; kb < 4; kb++) {
                bf16x8 bfrag = *(const bf16x8*)(brow + kb * 32);
                acc[nb] = __builtin_amdgcn_mfma_f32_16x16x32_bf16(afrag[kb], bfrag, acc[nb], 0, 0, 0);
            }
        }
        #pragma unroll
        for (int nb = 0; nb < 8; nb++) {
            int col = g * 128 + nb * 16 + m;
            float bb = bcat[col];
            #pragma unroll
            for (int r = 0; r < 4; r++) {
                int row = rowbase + w * 16 + q * 4 + r;
                if (row < N_NODES) outp[(size_t)row * 512 + col] = f2bf(acc[nb][r] + bb);
            }
        }
    }
}

// ---------------- fused q/k/v/skip projection GEMM (bf16 h input) ----------------
__global__ __launch_bounds__(256) void k_proj(
    const u16* __restrict__ hin, const u16* __restrict__ wt,
    const float* __restrict__ bcat, u16* __restrict__ outp)
{
    __shared__ u16 sA[64 * 136];
    __shared__ u16 sB[128 * 136];
    int t = threadIdx.x;
    int l = t & 63, w = t >> 6;
    int m = l & 15, q = l >> 4;
    int rowbase = blockIdx.x * 64;
    for (int c = t; c < 64 * 32; c += 256) {
        int row = c >> 5, ch = c & 31;
        int gr = rowbase + row;
        ushort4 pk = make_ushort4(0, 0, 0, 0);
        if (gr < N_NODES) pk = *(const ushort4*)&hin[(size_t)gr * 128 + ch * 4];
        *(ushort4*)&sA[row * 136 + ch * 4] = pk;
    }
    __syncthreads();
    bf16x8 afrag[4];
    #pragma unroll
    for (int kb = 0; kb < 4; kb++)
        afrag[kb] = *(const bf16x8*)&sA[(w * 16 + m) * 136 + kb * 32 + q * 8];

    f32x4 zf = {0.f, 0.f, 0.f, 0.f};
    for (int g = 0; g < 4; ++g) {
        __syncthreads();
        for (int c = t; c < 128 * 32; c += 256) {
            int row = c >> 5, ch = c & 31;
            *(ushort4*)&sB[row * 136 + ch * 4] = *(const ushort4*)&wt[(g * 128 + row) * 128 + ch * 4];
        }
        __syncthreads();
        f32x4 acc[8];
        #pragma unroll
        for (int nb = 0; nb < 8; nb++) acc[nb] = zf;
        #pragma unroll
        for (int nb = 0; nb < 8; nb++) {
            const u16* brow = &sB[(nb * 16 + m) * 136 + q * 8];
            #pragma unroll
            for (int kb = 0; kb < 4; kb++) {
                bf16x8 bfrag = *(const bf16x8*)(brow + kb * 32);
                acc[nb] = __builtin_amdgcn_mfma_f32_16x16x32_bf16(afrag[kb], bfrag, acc[nb], 0, 0, 0);
            }
        }
        #pragma unroll
        for (int nb = 0; nb < 8; nb++) {
            int col = g * 128 + nb * 16 + m;
            float bb = bcat[col];
            #pragma unroll
            for (int r = 0; r < 4; r++) {
                int row = rowbase + w * 16 + q * 4 + r;
                if (row < N_NODES) outp[(size_t)row * 512 + col] = f2bf(acc[nb][r] + bb);
            }
        }
    }
}

// ---------------- attention: wave per dst node, 4 subs x 16 lanes, no-max exp ----------------
__global__ __launch_bounds__(256) void k_attn(
    const u16* __restrict__ qkvs,
    const int* __restrict__ rowst, const int2* __restrict__ csr,
    const void* __restrict__ wep, u16* __restrict__ hout,
    const int* __restrict__ flag)
{
    int fl = getflag(flag);
    int t = threadIdx.x;
    int l = t & 63, w = t >> 6;
    int dstn = blockIdx.x * 4 + w;        // grid*4 == N exactly
    int lane16 = l & 15, sub = l >> 4;
    int f0 = lane16 * 8;                  // 8 features per lane
    const float scale = 0.17677669529663687f;  // 1/sqrt(32)

    bf16x8 q8 = *(const bf16x8*)&qkvs[(size_t)dstn * 512 + f0];
    float qf[8], wef[8];
    if (fl) {                              // vectorized wep load (wave-uniform branch)
        float4 w0 = *(const float4*)((const float*)wep + f0);
        float4 w1v = *(const float4*)((const float*)wep + f0 + 4);
        wef[0] = w0.x; wef[1] = w0.y; wef[2] = w0.z; wef[3] = w0.w;
        wef[4] = w1v.x; wef[5] = w1v.y; wef[6] = w1v.z; wef[7] = w1v.w;
    } else {
        bf16x8 w8 = *(const bf16x8*)((const u16*)wep + f0);
        #pragma unroll
        for (int j = 0; j < 8; j++) wef[j] = bf2f((u16)w8[j]);
    }
    #pragma unroll
    for (int j = 0; j < 8; j++) qf[j] = bf2f((u16)q8[j]) * scale;

    float si = 0.f;
    float a8[8];
    #pragma unroll
    for (int j = 0; j < 8; j++) a8[j] = 0.f;

    int rs = rowst[dstn], re = rowst[dstn + 1];
    int i = rs + sub;
    for (; i + 4 < re; i += 8) {
        int2 sa = csr[i];
        int2 sb = csr[i + 4];
        float ava = __int_as_float(sa.y);
        float avb = __int_as_float(sb.y);
        const u16* sra = &qkvs[(size_t)sa.x * 512 + f0];
        const u16* srb = &qkvs[(size_t)sb.x * 512 + f0];
        bf16x8 k8a = *(const bf16x8*)(sra + 128);
        bf16x8 v8a = *(const bf16x8*)(sra + 256);
        bf16x8 k8b = *(const bf16x8*)(srb + 128);
        bf16x8 v8b = *(const bf16x8*)(srb + 256);
        float pa = 0.f, pb = 0.f;
        float vea[8], veb[8];
        #pragma unroll
        for (int j = 0; j < 8; j++) {
            pa = fmaf(qf[j], fmaf(ava, wef[j], bf2f((u16)k8a[j])), pa);
            pb = fmaf(qf[j], fmaf(avb, wef[j], bf2f((u16)k8b[j])), pb);
            vea[j] = fmaf(ava, wef[j], bf2f((u16)v8a[j]));
            veb[j] = fmaf(avb, wef[j], bf2f((u16)v8b[j]));
        }
        pa += __shfl_xor(pa, 1); pb += __shfl_xor(pb, 1);
        pa += __shfl_xor(pa, 2); pb += __shfl_xor(pb, 2);
        float pea = __expf(pa);
        float peb = __expf(pb);
        si += pea + peb;
        #pragma unroll
        for (int j = 0; j < 8; j++)
            a8[j] = fmaf(pea, vea[j], fmaf(peb, veb[j], a8[j]));
    }
    if (i < re) {   // tail single edge
        int2 sa = csr[i];
        float av = __int_as_float(sa.y);
        const u16* sr = &qkvs[(size_t)sa.x * 512 + f0];
        bf16x8 k8 = *(const bf16x8*)(sr + 128);
        bf16x8 v8 = *(const bf16x8*)(sr + 256);
        float p = 0.f;
        float ve[8];
        #pragma unroll
        for (int j = 0; j < 8; j++) {
            p = fmaf(qf[j], fmaf(av, wef[j], bf2f((u16)k8[j])), p);
            ve[j] = fmaf(av, wef[j], bf2f((u16)v8[j]));
        }
        p += __shfl_xor(p, 1); p += __shfl_xor(p, 2);
        float pe = __expf(p);
        si += pe;
        #pragma unroll
        for (int j = 0; j < 8; j++) a8[j] = fmaf(pe, ve[j], a8[j]);
    }
    #pragma unroll
    for (int off = 16; off < 64; off <<= 1) {
        si += __shfl_xor(si, off);
        #pragma unroll
        for (int j = 0; j < 8; j++) a8[j] += __shfl_xor(a8[j], off);
    }
    if (sub == 0) {
        float inv = 1.f / (si + 1e-16f);
        bf16x8 s8 = *(const bf16x8*)&qkvs[(size_t)dstn * 512 + 384 + f0];
        ushort4 p0, p1;
        float o[8];
        #pragma unroll
        for (int j = 0; j < 8; j++)
            o[j] = fmaxf(fmaf(a8[j], inv, bf2f((u16)s8[j])), 0.f);
        p0.x = f2bf(o[0]); p0.y = f2bf(o[1]); p0.z = f2bf(o[2]); p0.w = f2bf(o[3]);
        p1.x = f2bf(o[4]); p1.y = f2bf(o[5]); p1.z = f2bf(o[6]); p1.w = f2bf(o[7]);
        u16* hr = hout + (size_t)dstn * 128 + f0;
        *(ushort4*)hr = p0;
        *(ushort4*)(hr + 4) = p1;
    }
}

// ---------------- global mean pool (bf16 h input, u32 feature pairs) ----------------
__global__ __launch_bounds__(256) void k_pool(
    const u16* __restrict__ h, const int* __restrict__ batch,
    float* __restrict__ gsum, float* __restrict__ gcnt)
{
    __shared__ float ssum[8 * 128];
    __shared__ float scnt[8];
    int t = threadIdx.x;
    for (int i = t; i < 8 * 128; i += 256) ssum[i] = 0.f;
    if (t < 8) scnt[t] = 0.f;
    __syncthreads();
    int f2 = (t & 63) * 2, quarter = t >> 6;
    int per = (N_NODES + gridDim.x - 1) / gridDim.x;
    int lo = blockIdx.x * per;
    int hi = lo + per; if (hi > N_NODES) hi = N_NODES;
    float r0 = 0.f, r1 = 0.f, rcnt = 0.f; int rg = -1;
    for (int n = lo + quarter; n < hi; n += 4) {
        int g = batch[n];
        if (g != rg) {
            if (rg >= 0) {
                atomicAdd(&ssum[rg * 128 + f2], r0);
                atomicAdd(&ssum[rg * 128 + f2 + 1], r1);
                if (f2 == 0) atomicAdd(&scnt[rg], rcnt);
            }
            rg = g; r0 = 0.f; r1 = 0.f; rcnt = 0.f;
        }
        u32 hv = *(const u32*)&h[(size_t)n * 128 + f2];
        r0 += bf2f((u16)(hv & 0xffff));
        r1 += bf2f((u16)(hv >> 16));
        rcnt += 1.f;
    }
    if (rg >= 0) {
        atomicAdd(&ssum[rg * 128 + f2], r0);
        atomicAdd(&ssum[rg * 128 + f2 + 1], r1);
        if (f2 == 0) atomicAdd(&scnt[rg], rcnt);
    }
    __syncthreads();
    for (int i = t; i < 8 * 128; i += 256) unsafeAtomicAdd(&gsum[i], ssum[i]);
    if (t < 8) unsafeAtomicAdd(&gcnt[t], scnt[t]);
}

__global__ void k_out(const float* __restrict__ gsum, const float* __restrict__ gcnt,
                      void* __restrict__ outp, const int* __restrict__ flag) {
    int fl = getflag(flag);
    int t = threadIdx.x;  // 1024
    float c = fmaxf(gcnt[t >> 7], 1.f);
    float v = gsum[t] / c;
    if (fl) ((float*)outp)[t] = v;
    else ((u16*)outp)[t] = f2bf(v);
}

extern "C" void kernel_launch(void* const* d_in, const int* in_sizes, int n_in,
                              void* d_out, int out_size, void* d_ws, size_t ws_size,
                              hipStream_t stream)
{
    (void)in_sizes; (void)n_in; (void)out_size; (void)ws_size;
    const void* x    = d_in[0];
    const int* ei    = (const int*)d_in[1];
    const void* ea   = d_in[2];
    const int* batch = (const int*)d_in[3];
    const void* w1   = d_in[4];
    const void* b1   = d_in[5];
    const void* lng  = d_in[6];
    const void* lnb  = d_in[7];
    const void* w2   = d_in[8];
    const void* b2   = d_in[9];
    const int* srcp = ei;
    const int* dstp = ei + N_EDGES;

    char* wsb = (char*)d_ws;
    size_t cur = 0;
    auto alloc = [&](size_t sz) -> void* {
        void* p = wsb + cur;
        cur += (sz + 255) & ~(size_t)255;
        return p;
    };
    u16*   y      = (u16*)  alloc((size_t)N_NODES * 128 * 2);
    u16*   h1     = (u16*)  alloc((size_t)N_NODES * 128 * 2);   // used as h3 (attn#2 out)
    u16*   h2     = (u16*)  alloc((size_t)N_NODES * 128 * 2);
    u16*   qkvs   = (u16*)  alloc((size_t)N_NODES * 512 * 2);
    int2*  csr    = (int2*) alloc((size_t)N_EDGES * 8);
    u16*   gt     = (u16*)  alloc(128 * 128 * 2);
    u16*   wcat1  = (u16*)  alloc(512 * 128 * 2);
    u16*   wcat2  = (u16*)  alloc(512 * 128 * 2);
    float* csum   = (float*)alloc(128 * 4);
    float* bwp    = (float*)alloc(128 * 4);
    u32*   w1pk   = (u32*)  alloc(64 * 4);
    float* bcat1  = (float*)alloc(512 * 4);
    float* bcat2  = (float*)alloc(512 * 4);
    int*   cntdeg = (int*)  alloc((size_t)N_NODES * 4);
    int*   rowst  = (int*)  alloc((size_t)(N_NODES + 1) * 4);
    int*   nxt    = (int*)  alloc((size_t)N_NODES * 4);
    float* gsum   = (float*)alloc((8 * 128 + 8) * 4);
    int*   dtflag = (int*)  alloc(256);
    // group-embed buffers (~26.8 MB total)
    float* h1stage = (float*)alloc((size_t)N_NODES * 128 * 4);
    float* vacc    = (float*)alloc((size_t)N_NODES * 4);
    int*   gstart  = (int*)  alloc((size_t)(N_NODES + 1) * 4);
    int2*  glist   = (int2*) alloc((size_t)NG_MAX * 8);
    u16*   h3 = h1;   // attn#2 writes h3 fully; pool reads it

    hipMemsetAsync(cntdeg, 0, (size_t)N_NODES * 4, stream);
    hipMemsetAsync(gsum, 0, (8 * 128 + 8) * 4, stream);
    hipMemsetAsync(h1stage, 0, (size_t)N_NODES * 128 * 4 + 256 + (size_t)N_NODES * 4, stream);

    P8 pw; P8 pb;
    pw.s[0] = d_in[10]; pw.s[1] = d_in[12]; pw.s[2] = d_in[14]; pw.s[3] = d_in[17];
    pw.s[4] = d_in[19]; pw.s[5] = d_in[21]; pw.s[6] = d_in[23]; pw.s[7] = d_in[26];
    pb.s[0] = d_in[11]; pb.s[1] = d_in[13]; pb.s[2] = d_in[15]; pb.s[3] = d_in[18];
    pb.s[4] = d_in[20]; pb.s[5] = d_in[22]; pb.s[6] = d_in[24]; pb.s[7] = d_in[27];

    k_deg_detect<<<3126, 256, 0, stream>>>(dstp, cntdeg, (const u16*)x, dtflag);
    k_prep_all<<<517, 256, 0, stream>>>(pw, pb, wcat1, wcat2, bcat1, bcat2,
                                        w2, lng, lnb, b2, w1, gt, csum, bwp, w1pk, dtflag);
    k_scan<<<1, 1024, 0, stream>>>(cntdeg, rowst, nxt, gstart);
    k_glist<<<196, 256, 0, stream>>>(rowst, gstart, glist);
    k_lin1_scatter<<<3907, 256, 0, stream>>>(x, w1, b1, y, dstp, srcp, ea, nxt, csr, dtflag);
    k_embed_grp<<<(NG_MAX + 7) / 8, 512, 0, stream>>>(y, csr, rowst, gstart, glist,
                                                      gt, w1pk, csum, bwp, h1stage, vacc);
    k_proj_fin<<<782, 256, 0, stream>>>(h1stage, vacc, rowst, lng, lnb,
                                        wcat1, bcat1, qkvs, dtflag);
    k_attn<<<12500, 256, 0, stream>>>(qkvs, rowst, csr, d_in[16], h2, dtflag);
    k_proj<<<782, 256, 0, stream>>>(h2, wcat2, bcat2, qkvs);
    k_attn<<<12500, 256, 0, stream>>>(qkvs, rowst, csr, d_in[25], h3, dtflag);
    k_pool<<<128, 256, 0, stream>>>(h3, batch, gsum, gsum + 8 * 128);
    k_out<<<1, 1024, 0, stream>>>(gsum, gsum + 8 * 128, d_out, dtflag);
}